// Round 12
// baseline (942.286 us; speedup 1.0000x reference)
//
#include <hip/hip_runtime.h>
#include <math.h>

#define B_SZ 4096
#define N_SZ 200
#define K_SZ 64
#define H1 80
#define H2 40
#define NEG_V (-4294967295.0f)

#define NFRAG 29          // 20 layer-1 frags + 9 layer-2 frags
#define WHALVES (NFRAG * 1024)   // halves in weight image (2 KB per frag)

typedef _Float16 f16x8 __attribute__((ext_vector_type(8)));
typedef float f32x4 __attribute__((ext_vector_type(4)));
typedef unsigned int u32;

union H2U { _Float16 h[2]; u32 u; };
union U4F { u32 u[4]; f16x8 v; };

typedef __attribute__((address_space(3))) u32 lds_u32;
typedef const __attribute__((address_space(1))) u32 glb_u32;

__device__ __forceinline__ void gload16(const void* gp, void* lp) {
    __builtin_amdgcn_global_load_lds((glb_u32*)gp, (lds_u32*)lp, 16, 0, 0);
}

// ---------------- qW[b][h] = b1[h] + sum_i q[b][i]*(W1[i][h]+W1[128+i][h])  (exact fp32)
__global__ __launch_bounds__(128) void qw_kernel(const float* __restrict__ query,
                                                 const float* __restrict__ W1,
                                                 const float* __restrict__ b1,
                                                 float* __restrict__ qW) {
    int b = blockIdx.x;
    int tid = threadIdx.x;
    __shared__ float sq[K_SZ];
    if (tid < K_SZ) sq[tid] = query[b * K_SZ + tid];
    __syncthreads();
    if (tid < H1) {
        float acc = b1[tid];
#pragma unroll 8
        for (int i = 0; i < K_SZ; ++i)
            acc += sq[i] * (W1[i * H1 + tid] + W1[(128 + i) * H1 + tid]);
        qW[b * H1 + tid] = acc;
    }
}

// ---------------- pack weights into the LDS image order (bank-swizzled, hi|lo 16B halves)
// frag f: lane l, elem j holds W[k = ks*32 + (l>>4)*8 + j][feat = ht*16 + (l&15)]
// image byte for (f,l,s=hi0/lo1): f*2048 + ((l*32 + s*16) ^ (((l>>2)&3)<<4)) + j*2
__global__ __launch_bounds__(256) void prep_bp(const float* __restrict__ W1,
                                               const float* __restrict__ W2,
                                               _Float16* __restrict__ Bp) {
    int idx = blockIdx.x * 256 + threadIdx.x;
    if (idx >= NFRAG * 512) return;
    int j = idx & 7, lane = (idx >> 3) & 63, f = idx >> 9;
    float w;
    if (f < 20) {                       // layer1: f = ht*4+ks
        int ks = f & 3, ht = f >> 2;
        int k = ks * 32 + (lane >> 4) * 8 + j;   // 0-63 k-coef, 64-127 q*k-coef
        int h = ht * 16 + (lane & 15);
        w = (k < 64) ? (W1[(64 + k) * H1 + h] - W1[(128 + k) * H1 + h])
                     : W1[(192 + (k - 64)) * H1 + h];
    } else {                            // layer2: f-20 = ht2*3+ks2
        int f2 = f - 20;
        int ks2 = f2 % 3, ht2 = f2 / 3;
        int k2 = ks2 * 32 + (lane >> 4) * 8 + j;
        int m = ht2 * 16 + (lane & 15);
        w = (k2 < H1 && m < H2) ? W2[k2 * H2 + m] : 0.0f;
    }
    _Float16 hi = (_Float16)w;
    _Float16 lo = (_Float16)(w - (float)hi);
    int swq = ((lane >> 2) & 3) << 4;
    int base = f * 1024;                // halves
    Bp[base + (((lane * 32) ^ swq) >> 1) + j] = hi;
    Bp[base + (((lane * 32 + 16) ^ swq) >> 1) + j] = lo;
}

// ---------------- fully fused, 2 batch rows per block (512 threads = 8 waves):
// weight image DMA->LDS once per block, 1-slot tile groups (fits 128-reg budget
// at 4 waves/SIMD), per-half softmax + value-weighted sum.
__global__ __launch_bounds__(512, 4) void fused_kernel(
    const float* __restrict__ query, const float* __restrict__ key,
    const float* __restrict__ value, const int* __restrict__ mask,
    const _Float16* __restrict__ BpG,
    const float* __restrict__ a1, const float* __restrict__ b2,
    const float* __restrict__ a2, const float* __restrict__ Wo,
    const float* __restrict__ bo, const float* __restrict__ qW,
    float* __restrict__ out) {
    __shared__ _Float16 wlds[WHALVES];   // 59,392 B weight image
    __shared__ float sq[2 * K_SZ];
    __shared__ float sqW[2 * H1];
    __shared__ float sa1[H1];
    __shared__ float sb2[48], sa2[48], sWo[48];
    __shared__ float sprob[2 * 256];
    __shared__ float sred[2 * 8];
    __shared__ float spart[8 * K_SZ];

    const int tid = threadIdx.x;
    const int wv = tid >> 6;         // 0..7
    const int l = tid & 63;
    const int l15 = l & 15;
    const int lg = l >> 4;
    const int half = wv >> 2;        // which b this wave works on
    const int wvh = wv & 3;          // wave index within half
    const int bx2 = blockIdx.x * 2;
    const int b = bx2 + half;
    const int p0 = b * N_SZ;
    const int NTW = (wvh == 0) ? 4 : 3;           // tiles for this wave
    const int tbW = (wvh == 0) ? 0 : 1 + wvh * 3; // first tile (within this b)

    // ---- stage weight image: 3712 16B chunks over 8 waves, linear dest
    {
#pragma unroll
        for (int i = 0; i < 7; ++i) {
            int cb = i * 512 + wv * 64;              // wave-uniform chunk base
            gload16(&BpG[(size_t)(cb + l) * 8], (char*)wlds + (size_t)cb * 16);
        }
        if (wv < 2) {                                // tail 128 chunks
            int cb = 3584 + wv * 64;
            gload16(&BpG[(size_t)(cb + l) * 8], (char*)wlds + (size_t)cb * 16);
        }
    }

    // ---- stage params (disjoint tid ranges)
    if (tid < 128) {
        sq[tid] = query[(size_t)(bx2 + (tid >> 6)) * K_SZ + (tid & 63)];
    } else if (tid < 288) {
        int i = tid - 128;           // 0..159
        int hh = i / H1, ii = i - hh * H1;
        sqW[i] = qW[(size_t)(bx2 + hh) * H1 + ii];
    } else if (tid < 368) {
        sa1[tid - 288] = a1[tid - 288];
    } else if (tid < 416) {
        int i = tid - 368; sb2[i] = (i < H2) ? b2[i] : 0.0f;
    } else if (tid < 464) {
        int i = tid - 416; sa2[i] = (i < H2) ? a2[i] : 0.0f;
    } else {
        int i = tid - 464; sWo[i] = (i < H2) ? Wo[i] : 0.0f;
    }
    float bov = bo[0];
    __syncthreads();    // drains weight DMA (vmcnt(0) before barrier)

    // per-lane swizzled weight offsets (halves)
    const int swq = ((l >> 2) & 3) << 4;
    const int offh = ((l * 32) ^ swq) >> 1;
    const int offl = ((l * 32 + 16) ^ swq) >> 1;

    // ---- compute this wave's tiles, ONE tile per group (register-lean)
#pragma unroll 1
    for (int it = 0; it < NTW; ++it) {
        const int ta = tbW + it;
        const int nloc = ta * 16 + l15;
        int pg = p0 + nloc;
        int pgc = (pg < B_SZ * N_SZ) ? pg : (B_SZ * N_SZ - 1);

        // feature frags from global (coalesced, L2/L3-cached)
        f16x8 Bk[2], Bqk[2];
#pragma unroll
        for (int ksp = 0; ksp < 2; ++ksp) {
            const float* kp = &key[(size_t)pgc * K_SZ + ksp * 32 + lg * 8];
            float4 k0 = *reinterpret_cast<const float4*>(kp);
            float4 k1 = *reinterpret_cast<const float4*>(kp + 4);
            const float* qp = &sq[half * K_SZ + ksp * 32 + lg * 8];
            float4 q0 = *reinterpret_cast<const float4*>(qp);
            float4 q1 = *reinterpret_cast<const float4*>(qp + 4);
            f16x8 bk, bq;
            bk[0] = (_Float16)k0.x; bk[1] = (_Float16)k0.y; bk[2] = (_Float16)k0.z; bk[3] = (_Float16)k0.w;
            bk[4] = (_Float16)k1.x; bk[5] = (_Float16)k1.y; bk[6] = (_Float16)k1.z; bk[7] = (_Float16)k1.w;
            bq[0] = (_Float16)(q0.x * k0.x); bq[1] = (_Float16)(q0.y * k0.y);
            bq[2] = (_Float16)(q0.z * k0.z); bq[3] = (_Float16)(q0.w * k0.w);
            bq[4] = (_Float16)(q1.x * k1.x); bq[5] = (_Float16)(q1.y * k1.y);
            bq[6] = (_Float16)(q1.z * k1.z); bq[7] = (_Float16)(q1.w * k1.w);
            Bk[ksp] = bk; Bqk[ksp] = bq;
        }

        // ---- layer 1
        f32x4 D1[5];
#pragma unroll
        for (int ht = 0; ht < 5; ++ht) D1[ht] = (f32x4){0.f, 0.f, 0.f, 0.f};
#pragma unroll
        for (int ht = 0; ht < 5; ++ht) {
#pragma unroll
            for (int kk = 0; kk < 4; ++kk) {     // ks tile: 0,1 = k-part; 2,3 = q*k-part
                int fb = (ht * 4 + kk) * 1024;
                f16x8 wh = *reinterpret_cast<const f16x8*>(&wlds[fb + offh]);
                f16x8 wl = *reinterpret_cast<const f16x8*>(&wlds[fb + offl]);
                f16x8 ff = (kk < 2) ? Bk[kk & 1] : Bqk[kk & 1];
                D1[ht] = __builtin_amdgcn_mfma_f32_16x16x32_f16(wh, ff, D1[ht], 0, 0, 0);
                D1[ht] = __builtin_amdgcn_mfma_f32_16x16x32_f16(wl, ff, D1[ht], 0, 0, 0);
            }
        }

        // ---- epilogue 1: h1 = prelu(D1 + qW) -> packed fp16 pairs
        u32 pk[6][2];
#pragma unroll
        for (int ht = 0; ht < 5; ++ht) {
            float4 qw4 = *reinterpret_cast<const float4*>(&sqW[half * H1 + ht * 16 + lg * 4]);
            float4 aa4 = *reinterpret_cast<const float4*>(&sa1[ht * 16 + lg * 4]);
            float h0 = D1[ht][0] + qw4.x;
            float h1v = D1[ht][1] + qw4.y;
            float h2 = D1[ht][2] + qw4.z;
            float h3 = D1[ht][3] + qw4.w;
            h0 = (h0 > 0.f) ? h0 : h0 * aa4.x;
            h1v = (h1v > 0.f) ? h1v : h1v * aa4.y;
            h2 = (h2 > 0.f) ? h2 : h2 * aa4.z;
            h3 = (h3 > 0.f) ? h3 : h3 * aa4.w;
            H2U u0, u1;
            u0.h[0] = (_Float16)h0; u0.h[1] = (_Float16)h1v;
            u1.h[0] = (_Float16)h2; u1.h[1] = (_Float16)h3;
            pk[ht][0] = u0.u;
            pk[ht][1] = u1.u;
        }
        pk[5][0] = 0u; pk[5][1] = 0u;   // zero-pad feats 80..95

        // ---- layer 2
        f32x4 D2[3];
#pragma unroll
        for (int ht = 0; ht < 3; ++ht) D2[ht] = (f32x4){0.f, 0.f, 0.f, 0.f};
#pragma unroll
        for (int ks2 = 0; ks2 < 3; ++ks2) {
            U4F bu;
#pragma unroll
            for (int q = 0; q < 4; ++q) {
                int src = ((lg * 2 + (q >> 1)) & 3) * 16 + l15;
                u32 va = (u32)__shfl((int)pk[ks2 * 2][q & 1], src, 64);
                u32 vb = (u32)__shfl((int)pk[ks2 * 2 + 1][q & 1], src, 64);
                bu.u[q] = (lg < 2) ? va : vb;
            }
            f16x8 B2f = bu.v;
#pragma unroll
            for (int ht2 = 0; ht2 < 3; ++ht2) {
                int fb = (20 + ht2 * 3 + ks2) * 1024;
                f16x8 wh = *reinterpret_cast<const f16x8*>(&wlds[fb + offh]);
                f16x8 wl = *reinterpret_cast<const f16x8*>(&wlds[fb + offl]);
                D2[ht2] = __builtin_amdgcn_mfma_f32_16x16x32_f16(wh, B2f, D2[ht2], 0, 0, 0);
                D2[ht2] = __builtin_amdgcn_mfma_f32_16x16x32_f16(wl, B2f, D2[ht2], 0, 0, 0);
            }
        }

        // ---- epilogue 2 + layer 3
        float psum = 0.f;
#pragma unroll
        for (int ht2 = 0; ht2 < 3; ++ht2) {
            float4 b4 = *reinterpret_cast<const float4*>(&sb2[ht2 * 16 + lg * 4]);
            float4 a4 = *reinterpret_cast<const float4*>(&sa2[ht2 * 16 + lg * 4]);
            float4 w4 = *reinterpret_cast<const float4*>(&sWo[ht2 * 16 + lg * 4]);
            float v0 = D2[ht2][0] + b4.x;
            float v1f = D2[ht2][1] + b4.y;
            float v2 = D2[ht2][2] + b4.z;
            float v3 = D2[ht2][3] + b4.w;
            v0 = (v0 > 0.f) ? v0 : v0 * a4.x;
            v1f = (v1f > 0.f) ? v1f : v1f * a4.y;
            v2 = (v2 > 0.f) ? v2 : v2 * a4.z;
            v3 = (v3 > 0.f) ? v3 : v3 * a4.w;
            psum += v0 * w4.x + v1f * w4.y + v2 * w4.z + v3 * w4.w;
        }
        psum += __shfl_xor(psum, 16);
        psum += __shfl_xor(psum, 32);
        if (lg == 0) {
            float sv;
            if (nloc < N_SZ) sv = (mask[p0 + nloc] == 0) ? NEG_V : (psum + bov);
            else sv = -INFINITY;
            sprob[half * 256 + nloc] = sv;
        }
    }
    __syncthreads();

    // ---- per-half softmax over 208 staged scores (pads -inf)
    const int t = tid & 255;
    const int hh = tid >> 8;
    float s = (t < 208) ? sprob[hh * 256 + t] : -INFINITY;
    float m = s;
#pragma unroll
    for (int off = 32; off >= 1; off >>= 1) m = fmaxf(m, __shfl_xor(m, off));
    if ((t & 63) == 0) sred[hh * 8 + (t >> 6)] = m;
    __syncthreads();
    m = fmaxf(fmaxf(sred[hh * 8 + 0], sred[hh * 8 + 1]),
              fmaxf(sred[hh * 8 + 2], sred[hh * 8 + 3]));

    float e = (t < 208) ? expf(s - m) : 0.0f;
    sprob[hh * 256 + t] = e;
    float tt = e;
#pragma unroll
    for (int off = 32; off >= 1; off >>= 1) tt += __shfl_xor(tt, off);
    if ((t & 63) == 0) sred[hh * 8 + 4 + (t >> 6)] = tt;
    __syncthreads();
    float inv = 1.0f / (sred[hh * 8 + 4] + sred[hh * 8 + 5] +
                        sred[hh * 8 + 6] + sred[hh * 8 + 7]);

    // ---- weighted value sum: wave covers rows [50*wvh, +50) of its half's b
    float acc0 = 0.0f, acc1v = 0.0f;
#pragma unroll 5
    for (int jj = 0; jj < 50; jj += 2) {
        int n = wvh * 50 + jj;
        acc0  += sprob[half * 256 + n]     * value[((size_t)p0 + n)     * K_SZ + l];
        acc1v += sprob[half * 256 + n + 1] * value[((size_t)p0 + n + 1) * K_SZ + l];
    }
    spart[wv * K_SZ + l] = acc0 + acc1v;
    __syncthreads();
    if (t < K_SZ) {
        int base = hh * 4 * K_SZ;
        out[(size_t)(bx2 + hh) * K_SZ + t] =
            (spart[base + t] + spart[base + K_SZ + t] +
             spart[base + 2 * K_SZ + t] + spart[base + 3 * K_SZ + t]) * inv;
    }
}

extern "C" void kernel_launch(void* const* d_in, const int* in_sizes, int n_in,
                              void* d_out, int out_size, void* d_ws, size_t ws_size,
                              hipStream_t stream) {
    const float* query = (const float*)d_in[0];
    const float* key   = (const float*)d_in[1];
    const float* value = (const float*)d_in[2];
    const int*   mask  = (const int*)d_in[3];
    const float* W1    = (const float*)d_in[4];
    const float* b1    = (const float*)d_in[5];
    const float* a1    = (const float*)d_in[6];
    const float* W2    = (const float*)d_in[7];
    const float* b2    = (const float*)d_in[8];
    const float* a2    = (const float*)d_in[9];
    const float* Wo    = (const float*)d_in[10];
    const float* bo    = (const float*)d_in[11];
    float* out = (float*)d_out;

    float* qW    = (float*)d_ws;                         // B*H1 floats
    _Float16* Bp = (_Float16*)(qW + (size_t)B_SZ * H1);  // NFRAG*1024 halves

    qw_kernel<<<B_SZ, 128, 0, stream>>>(query, W1, b1, qW);
    prep_bp<<<(NFRAG * 512 + 255) / 256, 256, 0, stream>>>(W1, W2, Bp);
    fused_kernel<<<B_SZ / 2, 512, 0, stream>>>(
        query, key, value, mask, Bp, a1, b2, a2, Wo, bo, qW, out);
}

// Round 15
// 364.079 us; speedup vs baseline: 2.5881x; 2.5881x over previous
//
#include <hip/hip_runtime.h>
#include <math.h>

#define B_SZ 4096
#define N_SZ 200
#define K_SZ 64
#define H1 80
#define H2 40
#define NEG_V (-4294967295.0f)

#define NFRAG 29          // 20 layer-1 frags (LDS) + 9 layer-2 frags (global/L1)
#define W1HALVES (20 * 1024)     // layer-1 halves in LDS image (40 KB)

typedef _Float16 f16x8 __attribute__((ext_vector_type(8)));
typedef float f32x4 __attribute__((ext_vector_type(4)));
typedef unsigned int u32;

union H2U { _Float16 h[2]; u32 u; };
union U4F { u32 u[4]; f16x8 v; };

typedef __attribute__((address_space(3))) u32 lds_u32;
typedef const __attribute__((address_space(1))) u32 glb_u32;

__device__ __forceinline__ void gload16(const void* gp, void* lp) {
    __builtin_amdgcn_global_load_lds((glb_u32*)gp, (lds_u32*)lp, 16, 0, 0);
}

// ---------------- qW[b][h] = b1[h] + sum_i q[b][i]*(W1[i][h]+W1[128+i][h])  (exact fp32)
__global__ __launch_bounds__(128) void qw_kernel(const float* __restrict__ query,
                                                 const float* __restrict__ W1,
                                                 const float* __restrict__ b1,
                                                 float* __restrict__ qW) {
    int b = blockIdx.x;
    int tid = threadIdx.x;
    __shared__ float sq[K_SZ];
    if (tid < K_SZ) sq[tid] = query[b * K_SZ + tid];
    __syncthreads();
    if (tid < H1) {
        float acc = b1[tid];
#pragma unroll 8
        for (int i = 0; i < K_SZ; ++i)
            acc += sq[i] * (W1[i * H1 + tid] + W1[(128 + i) * H1 + tid]);
        qW[b * H1 + tid] = acc;
    }
}

// ---------------- pack weights (bank-swizzled, hi|lo 16B halves, same layout both layers)
// frag f: lane l, elem j holds W[k = ks*32 + (l>>4)*8 + j][feat = ht*16 + (l&15)]
// image byte for (f,l,s=hi0/lo1): f*2048 + ((l*32 + s*16) ^ (((l>>2)&3)<<4)) + j*2
__global__ __launch_bounds__(256) void prep_bp(const float* __restrict__ W1,
                                               const float* __restrict__ W2,
                                               _Float16* __restrict__ Bp) {
    int idx = blockIdx.x * 256 + threadIdx.x;
    if (idx >= NFRAG * 512) return;
    int j = idx & 7, lane = (idx >> 3) & 63, f = idx >> 9;
    float w;
    if (f < 20) {                       // layer1: f = ht*4+ks
        int ks = f & 3, ht = f >> 2;
        int k = ks * 32 + (lane >> 4) * 8 + j;   // 0-63 k-coef, 64-127 q*k-coef
        int h = ht * 16 + (lane & 15);
        w = (k < 64) ? (W1[(64 + k) * H1 + h] - W1[(128 + k) * H1 + h])
                     : W1[(192 + (k - 64)) * H1 + h];
    } else {                            // layer2: f-20 = ht2*3+ks2
        int f2 = f - 20;
        int ks2 = f2 % 3, ht2 = f2 / 3;
        int k2 = ks2 * 32 + (lane >> 4) * 8 + j;
        int m = ht2 * 16 + (lane & 15);
        w = (k2 < H1 && m < H2) ? W2[k2 * H2 + m] : 0.0f;
    }
    _Float16 hi = (_Float16)w;
    _Float16 lo = (_Float16)(w - (float)hi);
    int swq = ((lane >> 2) & 3) << 4;
    int base = f * 1024;                // halves
    Bp[base + (((lane * 32) ^ swq) >> 1) + j] = hi;
    Bp[base + (((lane * 32 + 16) ^ swq) >> 1) + j] = lo;
}

// ---------------- fully fused: layer-1 weights DMA->LDS (40 KB), layer-2 weights
// from global (18 KB, L1-resident). One b per block, 4 waves, 2-slot tile groups
// {4,3,3,3}. Masked softmax + value-weighted sum fused.
__global__ __launch_bounds__(256, 3) void fused_kernel(
    const float* __restrict__ query, const float* __restrict__ key,
    const float* __restrict__ value, const int* __restrict__ mask,
    const _Float16* __restrict__ BpG,
    const float* __restrict__ a1, const float* __restrict__ b2,
    const float* __restrict__ a2, const float* __restrict__ Wo,
    const float* __restrict__ bo, const float* __restrict__ qW,
    float* __restrict__ out) {
    __shared__ _Float16 wlds[W1HALVES];  // 40,960 B layer-1 weight image
    __shared__ float sq[K_SZ];
    __shared__ float sqW[H1];
    __shared__ float sa1[H1];
    __shared__ float sb2[48], sa2[48], sWo[48];
    __shared__ float sprob[256];
    __shared__ float sred[8];
    __shared__ float spart[4 * K_SZ];

    const int tid = threadIdx.x;
    const int wv = tid >> 6;
    const int l = tid & 63;
    const int l15 = l & 15;
    const int lg = l >> 4;
    const int b = blockIdx.x;
    const int p0 = b * N_SZ;
    const int tb = (wv == 0) ? 0 : 1 + wv * 3;   // first tile; counts {4,3,3,3}

    // ---- stage layer-1 weight image: 2560 16B chunks over 4 waves, linear dest
    {
#pragma unroll
        for (int i = 0; i < 10; ++i) {
            int cb = i * 256 + wv * 64;              // wave-uniform chunk base
            gload16(&BpG[(size_t)(cb + l) * 8], (char*)wlds + (size_t)cb * 16);
        }
    }

    // ---- stage params
    if (tid < K_SZ) sq[tid] = query[b * K_SZ + tid];
    if (tid < H1) { sqW[tid] = qW[b * H1 + tid]; sa1[tid] = a1[tid]; }
    if (tid >= 128 && tid < 176) {
        int i = tid - 128;
        sb2[i] = (i < H2) ? b2[i] : 0.0f;
        sa2[i] = (i < H2) ? a2[i] : 0.0f;
        sWo[i] = (i < H2) ? Wo[i] : 0.0f;
    }
    float bov = bo[0];
    __syncthreads();    // drains weight DMA (vmcnt(0) before barrier)

    // per-lane swizzled weight offsets (halves), same for LDS and global image
    const int swq = ((l >> 2) & 3) << 4;
    const int offh = ((l * 32) ^ swq) >> 1;
    const int offl = ((l * 32 + 16) ^ swq) >> 1;

    // ---- compute 13 tiles in groups of <=2 slots per wave
    for (int g = 0; g < 2; ++g) {
        const int ta = tb + g * 2;
        const bool v1 = (g == 0) || (wv == 0);   // slot-1 validity

        // feature frags from global (coalesced, cached)
        f16x8 Bk[2][2], Bqk[2][2];
#pragma unroll
        for (int i = 0; i < 2; ++i) {
            if (i == 0 || v1) {
                int nloc = (ta + i) * 16 + l15;
                int pg = p0 + nloc;
                int pgc = (pg < B_SZ * N_SZ) ? pg : (B_SZ * N_SZ - 1);
#pragma unroll
                for (int ksp = 0; ksp < 2; ++ksp) {
                    const float* kp = &key[(size_t)pgc * K_SZ + ksp * 32 + lg * 8];
                    float4 k0 = *reinterpret_cast<const float4*>(kp);
                    float4 k1 = *reinterpret_cast<const float4*>(kp + 4);
                    const float* qp = &sq[ksp * 32 + lg * 8];
                    float4 q0 = *reinterpret_cast<const float4*>(qp);
                    float4 q1 = *reinterpret_cast<const float4*>(qp + 4);
                    f16x8 bk, bq;
                    bk[0] = (_Float16)k0.x; bk[1] = (_Float16)k0.y; bk[2] = (_Float16)k0.z; bk[3] = (_Float16)k0.w;
                    bk[4] = (_Float16)k1.x; bk[5] = (_Float16)k1.y; bk[6] = (_Float16)k1.z; bk[7] = (_Float16)k1.w;
                    bq[0] = (_Float16)(q0.x * k0.x); bq[1] = (_Float16)(q0.y * k0.y);
                    bq[2] = (_Float16)(q0.z * k0.z); bq[3] = (_Float16)(q0.w * k0.w);
                    bq[4] = (_Float16)(q1.x * k1.x); bq[5] = (_Float16)(q1.y * k1.y);
                    bq[6] = (_Float16)(q1.z * k1.z); bq[7] = (_Float16)(q1.w * k1.w);
                    Bk[i][ksp] = bk; Bqk[i][ksp] = bq;
                }
            }
        }

        // ---- layer 1 (weights from LDS)
        f32x4 D1[2][5];
#pragma unroll
        for (int i = 0; i < 2; ++i)
#pragma unroll
            for (int ht = 0; ht < 5; ++ht) D1[i][ht] = (f32x4){0.f, 0.f, 0.f, 0.f};
#pragma unroll
        for (int ht = 0; ht < 5; ++ht) {
#pragma unroll
            for (int kk = 0; kk < 4; ++kk) {     // 0,1 = k-part; 2,3 = q*k-part
                int fb = (ht * 4 + kk) * 1024;
                f16x8 wh = *reinterpret_cast<const f16x8*>(&wlds[fb + offh]);
                f16x8 wl = *reinterpret_cast<const f16x8*>(&wlds[fb + offl]);
                f16x8 f0 = (kk < 2) ? Bk[0][kk & 1] : Bqk[0][kk & 1];
                D1[0][ht] = __builtin_amdgcn_mfma_f32_16x16x32_f16(wh, f0, D1[0][ht], 0, 0, 0);
                D1[0][ht] = __builtin_amdgcn_mfma_f32_16x16x32_f16(wl, f0, D1[0][ht], 0, 0, 0);
                if (v1) {
                    f16x8 f1 = (kk < 2) ? Bk[1][kk & 1] : Bqk[1][kk & 1];
                    D1[1][ht] = __builtin_amdgcn_mfma_f32_16x16x32_f16(wh, f1, D1[1][ht], 0, 0, 0);
                    D1[1][ht] = __builtin_amdgcn_mfma_f32_16x16x32_f16(wl, f1, D1[1][ht], 0, 0, 0);
                }
            }
        }

        // ---- epilogue 1: h1 = prelu(D1 + qW) -> packed fp16 pairs
        u32 pk[2][6][2];
#pragma unroll
        for (int i = 0; i < 2; ++i) {
            if (i == 0 || v1) {
#pragma unroll
                for (int ht = 0; ht < 5; ++ht) {
                    float4 qw4 = *reinterpret_cast<const float4*>(&sqW[ht * 16 + lg * 4]);
                    float4 aa4 = *reinterpret_cast<const float4*>(&sa1[ht * 16 + lg * 4]);
                    float h0 = D1[i][ht][0] + qw4.x;
                    float h1v = D1[i][ht][1] + qw4.y;
                    float h2 = D1[i][ht][2] + qw4.z;
                    float h3 = D1[i][ht][3] + qw4.w;
                    h0 = (h0 > 0.f) ? h0 : h0 * aa4.x;
                    h1v = (h1v > 0.f) ? h1v : h1v * aa4.y;
                    h2 = (h2 > 0.f) ? h2 : h2 * aa4.z;
                    h3 = (h3 > 0.f) ? h3 : h3 * aa4.w;
                    H2U u0, u1;
                    u0.h[0] = (_Float16)h0; u0.h[1] = (_Float16)h1v;
                    u1.h[0] = (_Float16)h2; u1.h[1] = (_Float16)h3;
                    pk[i][ht][0] = u0.u;
                    pk[i][ht][1] = u1.u;
                }
                pk[i][5][0] = 0u; pk[i][5][1] = 0u;   // zero-pad feats 80..95
            }
        }

        // ---- layer 2 (weights from global, 18 KB L1-resident)
        f32x4 D2[2][3];
#pragma unroll
        for (int i = 0; i < 2; ++i)
#pragma unroll
            for (int ht = 0; ht < 3; ++ht) D2[i][ht] = (f32x4){0.f, 0.f, 0.f, 0.f};
#pragma unroll
        for (int ks2 = 0; ks2 < 3; ++ks2) {
            f16x8 B2f[2];
#pragma unroll
            for (int i = 0; i < 2; ++i) {
                if (i == 0 || v1) {
                    U4F bu;
#pragma unroll
                    for (int q = 0; q < 4; ++q) {
                        int src = ((lg * 2 + (q >> 1)) & 3) * 16 + l15;
                        u32 va = (u32)__shfl((int)pk[i][ks2 * 2][q & 1], src, 64);
                        u32 vb = (u32)__shfl((int)pk[i][ks2 * 2 + 1][q & 1], src, 64);
                        bu.u[q] = (lg < 2) ? va : vb;
                    }
                    B2f[i] = bu.v;
                }
            }
#pragma unroll
            for (int ht2 = 0; ht2 < 3; ++ht2) {
                const _Float16* fbg = &BpG[(size_t)(20 + ht2 * 3 + ks2) * 1024];
                f16x8 wh = *reinterpret_cast<const f16x8*>(&fbg[offh]);
                f16x8 wl = *reinterpret_cast<const f16x8*>(&fbg[offl]);
                D2[0][ht2] = __builtin_amdgcn_mfma_f32_16x16x32_f16(wh, B2f[0], D2[0][ht2], 0, 0, 0);
                D2[0][ht2] = __builtin_amdgcn_mfma_f32_16x16x32_f16(wl, B2f[0], D2[0][ht2], 0, 0, 0);
                if (v1) {
                    D2[1][ht2] = __builtin_amdgcn_mfma_f32_16x16x32_f16(wh, B2f[1], D2[1][ht2], 0, 0, 0);
                    D2[1][ht2] = __builtin_amdgcn_mfma_f32_16x16x32_f16(wl, B2f[1], D2[1][ht2], 0, 0, 0);
                }
            }
        }

        // ---- epilogue 2 + layer 3
#pragma unroll
        for (int i = 0; i < 2; ++i) {
            if (i == 0 || v1) {
                float psum = 0.f;
#pragma unroll
                for (int ht2 = 0; ht2 < 3; ++ht2) {
                    float4 b4 = *reinterpret_cast<const float4*>(&sb2[ht2 * 16 + lg * 4]);
                    float4 a4 = *reinterpret_cast<const float4*>(&sa2[ht2 * 16 + lg * 4]);
                    float4 w4 = *reinterpret_cast<const float4*>(&sWo[ht2 * 16 + lg * 4]);
                    float v0 = D2[i][ht2][0] + b4.x;
                    float v1f = D2[i][ht2][1] + b4.y;
                    float v2 = D2[i][ht2][2] + b4.z;
                    float v3 = D2[i][ht2][3] + b4.w;
                    v0 = (v0 > 0.f) ? v0 : v0 * a4.x;
                    v1f = (v1f > 0.f) ? v1f : v1f * a4.y;
                    v2 = (v2 > 0.f) ? v2 : v2 * a4.z;
                    v3 = (v3 > 0.f) ? v3 : v3 * a4.w;
                    psum += v0 * w4.x + v1f * w4.y + v2 * w4.z + v3 * w4.w;
                }
                psum += __shfl_xor(psum, 16);
                psum += __shfl_xor(psum, 32);
                if (lg == 0) {
                    int nloc = (ta + i) * 16 + l15;
                    float sv;
                    if (nloc < N_SZ) sv = (mask[p0 + nloc] == 0) ? NEG_V : (psum + bov);
                    else sv = -INFINITY;
                    sprob[nloc] = sv;
                }
            }
        }
    }
    __syncthreads();

    // ---- softmax over the 208 staged scores (pads are -inf)
    float s = (tid < 208) ? sprob[tid] : -INFINITY;
    float m = s;
#pragma unroll
    for (int off = 32; off >= 1; off >>= 1) m = fmaxf(m, __shfl_xor(m, off));
    if ((tid & 63) == 0) sred[tid >> 6] = m;
    __syncthreads();
    m = fmaxf(fmaxf(sred[0], sred[1]), fmaxf(sred[2], sred[3]));

    float e = (tid < 208) ? expf(s - m) : 0.0f;
    sprob[tid] = e;
    float t = e;
#pragma unroll
    for (int off = 32; off >= 1; off >>= 1) t += __shfl_xor(t, off);
    if ((tid & 63) == 0) sred[4 + (tid >> 6)] = t;
    __syncthreads();
    float inv = 1.0f / (sred[4] + sred[5] + sred[6] + sred[7]);

    // ---- weighted value sum: wave wv covers n = [50wv, 50wv+50), lane = k index
    float acc0 = 0.0f, acc1v = 0.0f;
#pragma unroll 5
    for (int jj = 0; jj < 50; jj += 2) {
        int n = wv * 50 + jj;
        acc0  += sprob[n]     * value[((size_t)p0 + n)     * K_SZ + l];
        acc1v += sprob[n + 1] * value[((size_t)p0 + n + 1) * K_SZ + l];
    }
    spart[wv * K_SZ + l] = acc0 + acc1v;
    __syncthreads();
    if (tid < K_SZ) {
        out[b * K_SZ + tid] =
            (spart[tid] + spart[64 + tid] + spart[128 + tid] + spart[192 + tid]) * inv;
    }
}

extern "C" void kernel_launch(void* const* d_in, const int* in_sizes, int n_in,
                              void* d_out, int out_size, void* d_ws, size_t ws_size,
                              hipStream_t stream) {
    const float* query = (const float*)d_in[0];
    const float* key   = (const float*)d_in[1];
    const float* value = (const float*)d_in[2];
    const int*   mask  = (const int*)d_in[3];
    const float* W1    = (const float*)d_in[4];
    const float* b1    = (const float*)d_in[5];
    const float* a1    = (const float*)d_in[6];
    const float* W2    = (const float*)d_in[7];
    const float* b2    = (const float*)d_in[8];
    const float* a2    = (const float*)d_in[9];
    const float* Wo    = (const float*)d_in[10];
    const float* bo    = (const float*)d_in[11];
    float* out = (float*)d_out;

    float* qW    = (float*)d_ws;                         // B*H1 floats
    _Float16* Bp = (_Float16*)(qW + (size_t)B_SZ * H1);  // NFRAG*1024 halves

    qw_kernel<<<B_SZ, 128, 0, stream>>>(query, W1, b1, qW);
    prep_bp<<<(NFRAG * 512 + 255) / 256, 256, 0, stream>>>(W1, W2, Bp);
    fused_kernel<<<B_SZ, 256, 0, stream>>>(
        query, key, value, mask, Bp, a1, b2, a2, Wo, bo, qW, out);
}

// Round 16
// 287.277 us; speedup vs baseline: 3.2801x; 1.2673x over previous
//
#include <hip/hip_runtime.h>
#include <math.h>

#define B_SZ 4096
#define N_SZ 200
#define K_SZ 64
#define H1 80
#define H2 40
#define NEG_V (-4294967295.0f)

#define NFRAG 29          // 20 layer-1 frags (LDS) + 9 layer-2 frags (global/L1)
#define W1HALVES (20 * 1024)     // layer-1 halves in LDS image (40 KB)

typedef _Float16 f16x8 __attribute__((ext_vector_type(8)));
typedef float f32x4 __attribute__((ext_vector_type(4)));
typedef unsigned int u32;

union H2U { _Float16 h[2]; u32 u; };
union U4F { u32 u[4]; f16x8 v; };

typedef __attribute__((address_space(3))) u32 lds_u32;
typedef const __attribute__((address_space(1))) u32 glb_u32;

__device__ __forceinline__ void gload16(const void* gp, void* lp) {
    __builtin_amdgcn_global_load_lds((glb_u32*)gp, (lds_u32*)lp, 16, 0, 0);
}

// ---------------- qW[b][h] = b1[h] + sum_i q[b][i]*(W1[i][h]+W1[128+i][h])  (exact fp32)
__global__ __launch_bounds__(128) void qw_kernel(const float* __restrict__ query,
                                                 const float* __restrict__ W1,
                                                 const float* __restrict__ b1,
                                                 float* __restrict__ qW) {
    int b = blockIdx.x;
    int tid = threadIdx.x;
    __shared__ float sq[K_SZ];
    if (tid < K_SZ) sq[tid] = query[b * K_SZ + tid];
    __syncthreads();
    if (tid < H1) {
        float acc = b1[tid];
#pragma unroll 8
        for (int i = 0; i < K_SZ; ++i)
            acc += sq[i] * (W1[i * H1 + tid] + W1[(128 + i) * H1 + tid]);
        qW[b * H1 + tid] = acc;
    }
}

// ---------------- pack weights (bank-swizzled, hi|lo 16B halves, same layout both layers)
// frag f: lane l, elem j holds W[k = ks*32 + (l>>4)*8 + j][feat = ht*16 + (l&15)]
// image byte for (f,l,s=hi0/lo1): f*2048 + ((l*32 + s*16) ^ (((l>>2)&3)<<4)) + j*2
__global__ __launch_bounds__(256) void prep_bp(const float* __restrict__ W1,
                                               const float* __restrict__ W2,
                                               _Float16* __restrict__ Bp) {
    int idx = blockIdx.x * 256 + threadIdx.x;
    if (idx >= NFRAG * 512) return;
    int j = idx & 7, lane = (idx >> 3) & 63, f = idx >> 9;
    float w;
    if (f < 20) {                       // layer1: f = ht*4+ks
        int ks = f & 3, ht = f >> 2;
        int k = ks * 32 + (lane >> 4) * 8 + j;   // 0-63 k-coef, 64-127 q*k-coef
        int h = ht * 16 + (lane & 15);
        w = (k < 64) ? (W1[(64 + k) * H1 + h] - W1[(128 + k) * H1 + h])
                     : W1[(192 + (k - 64)) * H1 + h];
    } else {                            // layer2: f-20 = ht2*3+ks2
        int f2 = f - 20;
        int ks2 = f2 % 3, ht2 = f2 / 3;
        int k2 = ks2 * 32 + (lane >> 4) * 8 + j;
        int m = ht2 * 16 + (lane & 15);
        w = (k2 < H1 && m < H2) ? W2[k2 * H2 + m] : 0.0f;
    }
    _Float16 hi = (_Float16)w;
    _Float16 lo = (_Float16)(w - (float)hi);
    int swq = ((lane >> 2) & 3) << 4;
    int base = f * 1024;                // halves
    Bp[base + (((lane * 32) ^ swq) >> 1) + j] = hi;
    Bp[base + (((lane * 32 + 16) ^ swq) >> 1) + j] = lo;
}

// ---------------- fully fused: layer-1 weights DMA->LDS (40 KB), layer-2 weights
// from global (18 KB, L1-resident). One b per block, 4 waves, ONE tile per loop
// iteration (register-lean, no launch-bounds clamp). Tiles {4,3,3,3}.
__global__ __launch_bounds__(256) void fused_kernel(
    const float* __restrict__ query, const float* __restrict__ key,
    const float* __restrict__ value, const int* __restrict__ mask,
    const _Float16* __restrict__ BpG,
    const float* __restrict__ a1, const float* __restrict__ b2,
    const float* __restrict__ a2, const float* __restrict__ Wo,
    const float* __restrict__ bo, const float* __restrict__ qW,
    float* __restrict__ out) {
    __shared__ _Float16 wlds[W1HALVES];  // 40,960 B layer-1 weight image
    __shared__ float sq[K_SZ];
    __shared__ float sqW[H1];
    __shared__ float sa1[H1];
    __shared__ float sb2[48], sa2[48], sWo[48];
    __shared__ float sprob[256];
    __shared__ float sred[8];
    __shared__ float spart[4 * K_SZ];

    const int tid = threadIdx.x;
    const int wv = tid >> 6;
    const int l = tid & 63;
    const int l15 = l & 15;
    const int lg = l >> 4;
    const int b = blockIdx.x;
    const int p0 = b * N_SZ;
    const int NTW = (wv == 0) ? 4 : 3;            // tiles for this wave
    const int tbW = (wv == 0) ? 0 : 1 + wv * 3;   // first tile

    // ---- stage layer-1 weight image: 2560 16B chunks over 4 waves, linear dest
    {
#pragma unroll
        for (int i = 0; i < 10; ++i) {
            int cb = i * 256 + wv * 64;              // wave-uniform chunk base
            gload16(&BpG[(size_t)(cb + l) * 8], (char*)wlds + (size_t)cb * 16);
        }
    }

    // ---- stage params
    if (tid < K_SZ) sq[tid] = query[b * K_SZ + tid];
    if (tid < H1) { sqW[tid] = qW[b * H1 + tid]; sa1[tid] = a1[tid]; }
    if (tid >= 128 && tid < 176) {
        int i = tid - 128;
        sb2[i] = (i < H2) ? b2[i] : 0.0f;
        sa2[i] = (i < H2) ? a2[i] : 0.0f;
        sWo[i] = (i < H2) ? Wo[i] : 0.0f;
    }
    float bov = bo[0];
    __syncthreads();    // drains weight DMA (vmcnt(0) before barrier)

    // per-lane swizzled weight offsets (halves), same for LDS and global image
    const int swq = ((l >> 2) & 3) << 4;
    const int offh = ((l * 32) ^ swq) >> 1;
    const int offl = ((l * 32 + 16) ^ swq) >> 1;

    // ---- compute this wave's tiles, ONE tile per iteration (register-lean)
#pragma unroll 1
    for (int it = 0; it < NTW; ++it) {
        const int ta = tbW + it;
        const int nloc = ta * 16 + l15;
        int pg = p0 + nloc;
        int pgc = (pg < B_SZ * N_SZ) ? pg : (B_SZ * N_SZ - 1);

        // feature frags from global (coalesced, cached)
        f16x8 Bk[2], Bqk[2];
#pragma unroll
        for (int ksp = 0; ksp < 2; ++ksp) {
            const float* kp = &key[(size_t)pgc * K_SZ + ksp * 32 + lg * 8];
            float4 k0 = *reinterpret_cast<const float4*>(kp);
            float4 k1 = *reinterpret_cast<const float4*>(kp + 4);
            const float* qp = &sq[ksp * 32 + lg * 8];
            float4 q0 = *reinterpret_cast<const float4*>(qp);
            float4 q1 = *reinterpret_cast<const float4*>(qp + 4);
            f16x8 bk, bq;
            bk[0] = (_Float16)k0.x; bk[1] = (_Float16)k0.y; bk[2] = (_Float16)k0.z; bk[3] = (_Float16)k0.w;
            bk[4] = (_Float16)k1.x; bk[5] = (_Float16)k1.y; bk[6] = (_Float16)k1.z; bk[7] = (_Float16)k1.w;
            bq[0] = (_Float16)(q0.x * k0.x); bq[1] = (_Float16)(q0.y * k0.y);
            bq[2] = (_Float16)(q0.z * k0.z); bq[3] = (_Float16)(q0.w * k0.w);
            bq[4] = (_Float16)(q1.x * k1.x); bq[5] = (_Float16)(q1.y * k1.y);
            bq[6] = (_Float16)(q1.z * k1.z); bq[7] = (_Float16)(q1.w * k1.w);
            Bk[ksp] = bk; Bqk[ksp] = bq;
        }

        // ---- layer 1 (weights from LDS)
        f32x4 D1[5];
#pragma unroll
        for (int ht = 0; ht < 5; ++ht) D1[ht] = (f32x4){0.f, 0.f, 0.f, 0.f};
#pragma unroll
        for (int ht = 0; ht < 5; ++ht) {
#pragma unroll
            for (int kk = 0; kk < 4; ++kk) {     // 0,1 = k-part; 2,3 = q*k-part
                int fb = (ht * 4 + kk) * 1024;
                f16x8 wh = *reinterpret_cast<const f16x8*>(&wlds[fb + offh]);
                f16x8 wl = *reinterpret_cast<const f16x8*>(&wlds[fb + offl]);
                f16x8 ff = (kk < 2) ? Bk[kk & 1] : Bqk[kk & 1];
                D1[ht] = __builtin_amdgcn_mfma_f32_16x16x32_f16(wh, ff, D1[ht], 0, 0, 0);
                D1[ht] = __builtin_amdgcn_mfma_f32_16x16x32_f16(wl, ff, D1[ht], 0, 0, 0);
            }
        }

        // ---- epilogue 1: h1 = prelu(D1 + qW) -> packed fp16 pairs
        u32 pk[6][2];
#pragma unroll
        for (int ht = 0; ht < 5; ++ht) {
            float4 qw4 = *reinterpret_cast<const float4*>(&sqW[ht * 16 + lg * 4]);
            float4 aa4 = *reinterpret_cast<const float4*>(&sa1[ht * 16 + lg * 4]);
            float h0 = D1[ht][0] + qw4.x;
            float h1v = D1[ht][1] + qw4.y;
            float h2 = D1[ht][2] + qw4.z;
            float h3 = D1[ht][3] + qw4.w;
            h0 = (h0 > 0.f) ? h0 : h0 * aa4.x;
            h1v = (h1v > 0.f) ? h1v : h1v * aa4.y;
            h2 = (h2 > 0.f) ? h2 : h2 * aa4.z;
            h3 = (h3 > 0.f) ? h3 : h3 * aa4.w;
            H2U u0, u1;
            u0.h[0] = (_Float16)h0; u0.h[1] = (_Float16)h1v;
            u1.h[0] = (_Float16)h2; u1.h[1] = (_Float16)h3;
            pk[ht][0] = u0.u;
            pk[ht][1] = u1.u;
        }
        pk[5][0] = 0u; pk[5][1] = 0u;   // zero-pad feats 80..95

        // ---- layer 2 (weights from global, 18 KB L1-resident)
        f32x4 D2[3];
#pragma unroll
        for (int ht = 0; ht < 3; ++ht) D2[ht] = (f32x4){0.f, 0.f, 0.f, 0.f};
#pragma unroll
        for (int ks2 = 0; ks2 < 3; ++ks2) {
            U4F bu;
#pragma unroll
            for (int q = 0; q < 4; ++q) {
                int src = ((lg * 2 + (q >> 1)) & 3) * 16 + l15;
                u32 va = (u32)__shfl((int)pk[ks2 * 2][q & 1], src, 64);
                u32 vb = (u32)__shfl((int)pk[ks2 * 2 + 1][q & 1], src, 64);
                bu.u[q] = (lg < 2) ? va : vb;
            }
            f16x8 B2f = bu.v;
#pragma unroll
            for (int ht2 = 0; ht2 < 3; ++ht2) {
                const _Float16* fbg = &BpG[(size_t)(20 + ht2 * 3 + ks2) * 1024];
                f16x8 wh = *reinterpret_cast<const f16x8*>(&fbg[offh]);
                f16x8 wl = *reinterpret_cast<const f16x8*>(&fbg[offl]);
                D2[ht2] = __builtin_amdgcn_mfma_f32_16x16x32_f16(wh, B2f, D2[ht2], 0, 0, 0);
                D2[ht2] = __builtin_amdgcn_mfma_f32_16x16x32_f16(wl, B2f, D2[ht2], 0, 0, 0);
            }
        }

        // ---- epilogue 2 + layer 3
        float psum = 0.f;
#pragma unroll
        for (int ht2 = 0; ht2 < 3; ++ht2) {
            float4 b4 = *reinterpret_cast<const float4*>(&sb2[ht2 * 16 + lg * 4]);
            float4 a4 = *reinterpret_cast<const float4*>(&sa2[ht2 * 16 + lg * 4]);
            float4 w4 = *reinterpret_cast<const float4*>(&sWo[ht2 * 16 + lg * 4]);
            float v0 = D2[ht2][0] + b4.x;
            float v1f = D2[ht2][1] + b4.y;
            float v2 = D2[ht2][2] + b4.z;
            float v3 = D2[ht2][3] + b4.w;
            v0 = (v0 > 0.f) ? v0 : v0 * a4.x;
            v1f = (v1f > 0.f) ? v1f : v1f * a4.y;
            v2 = (v2 > 0.f) ? v2 : v2 * a4.z;
            v3 = (v3 > 0.f) ? v3 : v3 * a4.w;
            psum += v0 * w4.x + v1f * w4.y + v2 * w4.z + v3 * w4.w;
        }
        psum += __shfl_xor(psum, 16);
        psum += __shfl_xor(psum, 32);
        if (lg == 0) {
            float sv;
            if (nloc < N_SZ) sv = (mask[p0 + nloc] == 0) ? NEG_V : (psum + bov);
            else sv = -INFINITY;
            sprob[nloc] = sv;
        }
    }
    __syncthreads();

    // ---- softmax over the 208 staged scores (pads are -inf)
    float s = (tid < 208) ? sprob[tid] : -INFINITY;
    float m = s;
#pragma unroll
    for (int off = 32; off >= 1; off >>= 1) m = fmaxf(m, __shfl_xor(m, off));
    if ((tid & 63) == 0) sred[tid >> 6] = m;
    __syncthreads();
    m = fmaxf(fmaxf(sred[0], sred[1]), fmaxf(sred[2], sred[3]));

    float e = (tid < 208) ? expf(s - m) : 0.0f;
    sprob[tid] = e;
    float t = e;
#pragma unroll
    for (int off = 32; off >= 1; off >>= 1) t += __shfl_xor(t, off);
    if ((tid & 63) == 0) sred[4 + (tid >> 6)] = t;
    __syncthreads();
    float inv = 1.0f / (sred[4] + sred[5] + sred[6] + sred[7]);

    // ---- weighted value sum: wave wv covers n = [50wv, 50wv+50), lane = k index
    float acc0 = 0.0f, acc1v = 0.0f;
#pragma unroll 5
    for (int jj = 0; jj < 50; jj += 2) {
        int n = wv * 50 + jj;
        acc0  += sprob[n]     * value[((size_t)p0 + n)     * K_SZ + l];
        acc1v += sprob[n + 1] * value[((size_t)p0 + n + 1) * K_SZ + l];
    }
    spart[wv * K_SZ + l] = acc0 + acc1v;
    __syncthreads();
    if (tid < K_SZ) {
        out[b * K_SZ + tid] =
            (spart[tid] + spart[64 + tid] + spart[128 + tid] + spart[192 + tid]) * inv;
    }
}

extern "C" void kernel_launch(void* const* d_in, const int* in_sizes, int n_in,
                              void* d_out, int out_size, void* d_ws, size_t ws_size,
                              hipStream_t stream) {
    const float* query = (const float*)d_in[0];
    const float* key   = (const float*)d_in[1];
    const float* value = (const float*)d_in[2];
    const int*   mask  = (const int*)d_in[3];
    const float* W1    = (const float*)d_in[4];
    const float* b1    = (const float*)d_in[5];
    const float* a1    = (const float*)d_in[6];
    const float* W2    = (const float*)d_in[7];
    const float* b2    = (const float*)d_in[8];
    const float* a2    = (const float*)d_in[9];
    const float* Wo    = (const float*)d_in[10];
    const float* bo    = (const float*)d_in[11];
    float* out = (float*)d_out;

    float* qW    = (float*)d_ws;                         // B*H1 floats
    _Float16* Bp = (_Float16*)(qW + (size_t)B_SZ * H1);  // NFRAG*1024 halves

    qw_kernel<<<B_SZ, 128, 0, stream>>>(query, W1, b1, qW);
    prep_bp<<<(NFRAG * 512 + 255) / 256, 256, 0, stream>>>(W1, W2, Bp);
    fused_kernel<<<B_SZ, 256, 0, stream>>>(
        query, key, value, mask, Bp, a1, b2, a2, Wo, bo, qW, out);
}

// Round 17
// 146.627 us; speedup vs baseline: 6.4264x; 1.9592x over previous
//
#include <hip/hip_runtime.h>
#include <math.h>

#define B_SZ 4096
#define N_SZ 200
#define K_SZ 64
#define H1 80
#define H2 40
#define NEG_V (-4294967295.0f)

#define NFRAG 29                 // 20 layer-1 frags + 9 layer-2 frags (all in LDS)
#define WHALVES (NFRAG * 512)    // single-fp16 weight image: 29,696 B
#define WCHUNKS (WHALVES / 8)    // 1856 16B chunks

typedef _Float16 f16x8 __attribute__((ext_vector_type(8)));
typedef float f32x4 __attribute__((ext_vector_type(4)));
typedef unsigned int u32;

union H2U { _Float16 h[2]; u32 u; };
union U4F { u32 u[4]; f16x8 v; };

typedef __attribute__((address_space(3))) u32 lds_u32;
typedef const __attribute__((address_space(1))) u32 glb_u32;

__device__ __forceinline__ void gload16(const void* gp, void* lp) {
    __builtin_amdgcn_global_load_lds((glb_u32*)gp, (lds_u32*)lp, 16, 0, 0);
}

// ---------------- qW[b][h] = b1[h] + sum_i q[b][i]*(W1[i][h]+W1[128+i][h])  (exact fp32)
__global__ __launch_bounds__(128) void qw_kernel(const float* __restrict__ query,
                                                 const float* __restrict__ W1,
                                                 const float* __restrict__ b1,
                                                 float* __restrict__ qW) {
    int b = blockIdx.x;
    int tid = threadIdx.x;
    __shared__ float sq[K_SZ];
    if (tid < K_SZ) sq[tid] = query[b * K_SZ + tid];
    __syncthreads();
    if (tid < H1) {
        float acc = b1[tid];
#pragma unroll 8
        for (int i = 0; i < K_SZ; ++i)
            acc += sq[i] * (W1[i * H1 + tid] + W1[(128 + i) * H1 + tid]);
        qW[b * H1 + tid] = acc;
    }
}

// ---------------- pack weights, single fp16, MFMA A-frag order, linear image
// frag f: lane l, elem j holds W[k = ks*32 + (l>>4)*8 + j][feat = ht*16 + (l&15)]
// image half index: (f*64 + l)*8 + j
__global__ __launch_bounds__(256) void prep_bp(const float* __restrict__ W1,
                                               const float* __restrict__ W2,
                                               _Float16* __restrict__ Bp) {
    int idx = blockIdx.x * 256 + threadIdx.x;
    if (idx >= NFRAG * 512) return;
    int j = idx & 7, lane = (idx >> 3) & 63, f = idx >> 9;
    float w;
    if (f < 20) {                       // layer1: f = ht*4+ks
        int ks = f & 3, ht = f >> 2;
        int k = ks * 32 + (lane >> 4) * 8 + j;   // 0-63 k-coef, 64-127 q*k-coef
        int h = ht * 16 + (lane & 15);
        w = (k < 64) ? (W1[(64 + k) * H1 + h] - W1[(128 + k) * H1 + h])
                     : W1[(192 + (k - 64)) * H1 + h];
    } else {                            // layer2: f-20 = ht2*3+ks2
        int f2 = f - 20;
        int ks2 = f2 % 3, ht2 = f2 / 3;
        int k2 = ks2 * 32 + (lane >> 4) * 8 + j;
        int m = ht2 * 16 + (lane & 15);
        w = (k2 < H1 && m < H2) ? W2[k2 * H2 + m] : 0.0f;
    }
    Bp[(size_t)(f * 64 + lane) * 8 + j] = (_Float16)w;
}

// ---------------- fully fused: single-fp16 weight image DMA->LDS (29 KB),
// MLP scores via swapped MFMA (4-slot {4,3,3,3}), masked softmax, value sum.
__global__ __launch_bounds__(256, 4) void fused_kernel(
    const float* __restrict__ query, const float* __restrict__ key,
    const float* __restrict__ value, const int* __restrict__ mask,
    const _Float16* __restrict__ BpG,
    const float* __restrict__ a1, const float* __restrict__ b2,
    const float* __restrict__ a2, const float* __restrict__ Wo,
    const float* __restrict__ bo, const float* __restrict__ qW,
    float* __restrict__ out) {
    __shared__ _Float16 wlds[WHALVES];   // 29,696 B weight image
    __shared__ float sq[K_SZ];
    __shared__ float sqW[H1];
    __shared__ float sa1[H1];
    __shared__ float sb2[48], sa2[48], sWo[48];
    __shared__ float sprob[256];
    __shared__ float sred[8];
    __shared__ float spart[4 * K_SZ];

    const int tid = threadIdx.x;
    const int wv = tid >> 6;
    const int l = tid & 63;
    const int l15 = l & 15;
    const int lg = l >> 4;
    const int b = blockIdx.x;
    const int p0 = b * N_SZ;
    const int NT = (wv == 0) ? 4 : 3;
    const int tb = (wv == 0) ? 0 : 1 + wv * 3;

    // ---- stage weight image: 1856 16B chunks, coalesced DMA, linear dest
    {
#pragma unroll
        for (int i = 0; i < 7; ++i) {
            int cb = i * 256 + wv * 64;              // wave-uniform chunk base
            gload16(&BpG[(size_t)(cb + l) * 8], (char*)wlds + (size_t)cb * 16);
        }
        if (wv == 0) {                               // tail 64 chunks
            int cb = 7 * 256;
            gload16(&BpG[(size_t)(cb + l) * 8], (char*)wlds + (size_t)cb * 16);
        }
    }

    // ---- stage params
    if (tid < K_SZ) sq[tid] = query[b * K_SZ + tid];
    if (tid < H1) { sqW[tid] = qW[b * H1 + tid]; sa1[tid] = a1[tid]; }
    if (tid >= 128 && tid < 176) {
        int i = tid - 128;
        sb2[i] = (i < H2) ? b2[i] : 0.0f;
        sa2[i] = (i < H2) ? a2[i] : 0.0f;
        sWo[i] = (i < H2) ? Wo[i] : 0.0f;
    }
    float bov = bo[0];
    __syncthreads();    // drains weight DMA (vmcnt(0) before barrier)

    const int wofs = l * 8;   // lane's halves offset within a frag (linear, conflict-free)

    // ---- layer 1: D1[f][n] = sum_k W1c[k][f] * F[k][n]
    f32x4 D1[4][5];
#pragma unroll
    for (int i = 0; i < 4; ++i)
#pragma unroll
        for (int ht = 0; ht < 5; ++ht) D1[i][ht] = (f32x4){0.f, 0.f, 0.f, 0.f};

#pragma unroll
    for (int ksp = 0; ksp < 2; ++ksp) {
        const float* qp = &sq[ksp * 32 + lg * 8];
        float4 q0 = *reinterpret_cast<const float4*>(qp);
        float4 q1 = *reinterpret_cast<const float4*>(qp + 4);
        f16x8 Bk[4], Bqk[4];
#pragma unroll
        for (int i = 0; i < 4; ++i) {
            if (i < NT) {
                int nloc = (tb + i) * 16 + l15;
                int pg = p0 + nloc;
                int pgc = (pg < B_SZ * N_SZ) ? pg : (B_SZ * N_SZ - 1);
                const float* kp = &key[(size_t)pgc * K_SZ + ksp * 32 + lg * 8];
                float4 k0 = *reinterpret_cast<const float4*>(kp);
                float4 k1 = *reinterpret_cast<const float4*>(kp + 4);
                f16x8 bk, bq;
                bk[0] = (_Float16)k0.x; bk[1] = (_Float16)k0.y; bk[2] = (_Float16)k0.z; bk[3] = (_Float16)k0.w;
                bk[4] = (_Float16)k1.x; bk[5] = (_Float16)k1.y; bk[6] = (_Float16)k1.z; bk[7] = (_Float16)k1.w;
                bq[0] = (_Float16)(q0.x * k0.x); bq[1] = (_Float16)(q0.y * k0.y);
                bq[2] = (_Float16)(q0.z * k0.z); bq[3] = (_Float16)(q0.w * k0.w);
                bq[4] = (_Float16)(q1.x * k1.x); bq[5] = (_Float16)(q1.y * k1.y);
                bq[6] = (_Float16)(q1.z * k1.z); bq[7] = (_Float16)(q1.w * k1.w);
                Bk[i] = bk; Bqk[i] = bq;
            }
        }
#pragma unroll
        for (int ht = 0; ht < 5; ++ht) {
#pragma unroll
            for (int s = 0; s < 2; ++s) {
                int kk = ksp + s * 2;                 // weight k-tile index
                f16x8 wh = *reinterpret_cast<const f16x8*>(&wlds[(ht * 4 + kk) * 512 + wofs]);
#pragma unroll
                for (int i = 0; i < 4; ++i) {
                    if (i < NT) {
                        f16x8 bb = (s == 0) ? Bk[i] : Bqk[i];
                        D1[i][ht] = __builtin_amdgcn_mfma_f32_16x16x32_f16(wh, bb, D1[i][ht], 0, 0, 0);
                    }
                }
            }
        }
    }

    // ---- epilogue 1 (in-register): h1 = prelu(D1 + qW), pack to fp16 pairs
    u32 pk[4][6][2];
#pragma unroll
    for (int i = 0; i < 4; ++i) {
        if (i < NT) {
#pragma unroll
            for (int ht = 0; ht < 5; ++ht) {
                float4 qw4 = *reinterpret_cast<const float4*>(&sqW[ht * 16 + lg * 4]);
                float4 aa4 = *reinterpret_cast<const float4*>(&sa1[ht * 16 + lg * 4]);
                float h0 = D1[i][ht][0] + qw4.x;
                float h1v = D1[i][ht][1] + qw4.y;
                float h2 = D1[i][ht][2] + qw4.z;
                float h3 = D1[i][ht][3] + qw4.w;
                h0 = (h0 > 0.f) ? h0 : h0 * aa4.x;
                h1v = (h1v > 0.f) ? h1v : h1v * aa4.y;
                h2 = (h2 > 0.f) ? h2 : h2 * aa4.z;
                h3 = (h3 > 0.f) ? h3 : h3 * aa4.w;
                H2U u0, u1;
                u0.h[0] = (_Float16)h0; u0.h[1] = (_Float16)h1v;
                u1.h[0] = (_Float16)h2; u1.h[1] = (_Float16)h3;
                pk[i][ht][0] = u0.u;
                pk[i][ht][1] = u1.u;
            }
            pk[i][5][0] = 0u; pk[i][5][1] = 0u;   // zero-pad feats 80..95
        }
    }

    // ---- layer 2: D2[m][n] = sum_k2 W2[k2][m] * h1[k2][n]
    f32x4 D2[4][3];
#pragma unroll
    for (int i = 0; i < 4; ++i)
#pragma unroll
        for (int ht = 0; ht < 3; ++ht) D2[i][ht] = (f32x4){0.f, 0.f, 0.f, 0.f};

#pragma unroll
    for (int ks2 = 0; ks2 < 3; ++ks2) {
        f16x8 B2f[4];
#pragma unroll
        for (int i = 0; i < 4; ++i) {
            if (i < NT) {
                U4F bu;
#pragma unroll
                for (int q = 0; q < 4; ++q) {
                    int src = ((lg * 2 + (q >> 1)) & 3) * 16 + l15;
                    u32 va = (u32)__shfl((int)pk[i][ks2 * 2][q & 1], src, 64);
                    u32 vb = (u32)__shfl((int)pk[i][ks2 * 2 + 1][q & 1], src, 64);
                    bu.u[q] = (lg < 2) ? va : vb;
                }
                B2f[i] = bu.v;
            }
        }
#pragma unroll
        for (int ht2 = 0; ht2 < 3; ++ht2) {
            f16x8 wh = *reinterpret_cast<const f16x8*>(&wlds[(20 + ht2 * 3 + ks2) * 512 + wofs]);
#pragma unroll
            for (int i = 0; i < 4; ++i) {
                if (i < NT) {
                    D2[i][ht2] = __builtin_amdgcn_mfma_f32_16x16x32_f16(wh, B2f[i], D2[i][ht2], 0, 0, 0);
                }
            }
        }
    }

    // ---- epilogue 2 + layer 3: score(n) = bo + sum_m Wo[m]*prelu(D2[m][n]+b2[m])
#pragma unroll
    for (int i = 0; i < 4; ++i) {
        if (i < NT) {
            float psum = 0.f;
#pragma unroll
            for (int ht2 = 0; ht2 < 3; ++ht2) {
                float4 b4 = *reinterpret_cast<const float4*>(&sb2[ht2 * 16 + lg * 4]);
                float4 a4 = *reinterpret_cast<const float4*>(&sa2[ht2 * 16 + lg * 4]);
                float4 w4 = *reinterpret_cast<const float4*>(&sWo[ht2 * 16 + lg * 4]);
                float v0 = D2[i][ht2][0] + b4.x;
                float v1 = D2[i][ht2][1] + b4.y;
                float v2 = D2[i][ht2][2] + b4.z;
                float v3 = D2[i][ht2][3] + b4.w;
                v0 = (v0 > 0.f) ? v0 : v0 * a4.x;
                v1 = (v1 > 0.f) ? v1 : v1 * a4.y;
                v2 = (v2 > 0.f) ? v2 : v2 * a4.z;
                v3 = (v3 > 0.f) ? v3 : v3 * a4.w;
                psum += v0 * w4.x + v1 * w4.y + v2 * w4.z + v3 * w4.w;
            }
            psum += __shfl_xor(psum, 16);
            psum += __shfl_xor(psum, 32);
            if (lg == 0) {
                int nloc = (tb + i) * 16 + l15;
                float sv;
                if (nloc < N_SZ) sv = (mask[p0 + nloc] == 0) ? NEG_V : (psum + bov);
                else sv = -INFINITY;
                sprob[nloc] = sv;
            }
        }
    }
    __syncthreads();

    // ---- softmax over the 208 staged scores (pads are -inf)
    float s = (tid < 208) ? sprob[tid] : -INFINITY;
    float m = s;
#pragma unroll
    for (int off = 32; off >= 1; off >>= 1) m = fmaxf(m, __shfl_xor(m, off));
    if ((tid & 63) == 0) sred[tid >> 6] = m;
    __syncthreads();
    m = fmaxf(fmaxf(sred[0], sred[1]), fmaxf(sred[2], sred[3]));

    float e = (tid < 208) ? expf(s - m) : 0.0f;
    sprob[tid] = e;
    float t = e;
#pragma unroll
    for (int off = 32; off >= 1; off >>= 1) t += __shfl_xor(t, off);
    if ((tid & 63) == 0) sred[4 + (tid >> 6)] = t;
    __syncthreads();
    float inv = 1.0f / (sred[4] + sred[5] + sred[6] + sred[7]);

    // ---- weighted value sum: wave wv covers n = [50wv, 50wv+50), lane = k index
    float acc0 = 0.0f, acc1v = 0.0f;
#pragma unroll 5
    for (int jj = 0; jj < 50; jj += 2) {
        int n = wv * 50 + jj;
        acc0  += sprob[n]     * value[((size_t)p0 + n)     * K_SZ + l];
        acc1v += sprob[n + 1] * value[((size_t)p0 + n + 1) * K_SZ + l];
    }
    spart[wv * K_SZ + l] = acc0 + acc1v;
    __syncthreads();
    if (tid < K_SZ) {
        out[b * K_SZ + tid] =
            (spart[tid] + spart[64 + tid] + spart[128 + tid] + spart[192 + tid]) * inv;
    }
}

extern "C" void kernel_launch(void* const* d_in, const int* in_sizes, int n_in,
                              void* d_out, int out_size, void* d_ws, size_t ws_size,
                              hipStream_t stream) {
    const float* query = (const float*)d_in[0];
    const float* key   = (const float*)d_in[1];
    const float* value = (const float*)d_in[2];
    const int*   mask  = (const int*)d_in[3];
    const float* W1    = (const float*)d_in[4];
    const float* b1    = (const float*)d_in[5];
    const float* a1    = (const float*)d_in[6];
    const float* W2    = (const float*)d_in[7];
    const float* b2    = (const float*)d_in[8];
    const float* a2    = (const float*)d_in[9];
    const float* Wo    = (const float*)d_in[10];
    const float* bo    = (const float*)d_in[11];
    float* out = (float*)d_out;

    float* qW    = (float*)d_ws;                         // B*H1 floats
    _Float16* Bp = (_Float16*)(qW + (size_t)B_SZ * H1);  // NFRAG*512 halves

    qw_kernel<<<B_SZ, 128, 0, stream>>>(query, W1, b1, qW);
    prep_bp<<<(NFRAG * 512 + 255) / 256, 256, 0, stream>>>(W1, W2, Bp);
    fused_kernel<<<B_SZ, 256, 0, stream>>>(
        query, key, value, mask, Bp, a1, b2, a2, Wo, bo, qW, out);
}

// Round 18
// 133.904 us; speedup vs baseline: 7.0371x; 1.0950x over previous
//
#include <hip/hip_runtime.h>
#include <math.h>

#define B_SZ 4096
#define N_SZ 200
#define K_SZ 64
#define H1 80
#define H2 40
#define NEG_V (-4294967295.0f)

#define NW1FRAG 10               // layer-1 W_eff frags (K=64: 2 ks x 5 ht)
#define NW2FRAG 9                // layer-2 frags (3 ks2 x 3 ht2)
#define W1ELT (NW1FRAG * 512)    // 5120 f32 elements in W1k/W1p images
#define W2HALVES (NW2FRAG * 512) // 4608 fp16 halves
#define WLDS_HALVES (NW1FRAG * 512 + NW2FRAG * 512)  // 9728 halves = 19,456 B

typedef _Float16 f16x8 __attribute__((ext_vector_type(8)));
typedef float f32x4 __attribute__((ext_vector_type(4)));
typedef unsigned int u32;

union H2U { _Float16 h[2]; u32 u; };
union U4F { u32 u[4]; f16x8 v; };

typedef __attribute__((address_space(3))) u32 lds_u32;
typedef const __attribute__((address_space(1))) u32 glb_u32;

__device__ __forceinline__ void gload16(const void* gp, void* lp) {
    __builtin_amdgcn_global_load_lds((glb_u32*)gp, (lds_u32*)lp, 16, 0, 0);
}

// ---------------- qW[b][h] = b1[h] + sum_i q[b][i]*(W1[i][h]+W1[128+i][h])  (exact fp32)
__global__ __launch_bounds__(128) void qw_kernel(const float* __restrict__ query,
                                                 const float* __restrict__ W1,
                                                 const float* __restrict__ b1,
                                                 float* __restrict__ qW) {
    int b = blockIdx.x;
    int tid = threadIdx.x;
    __shared__ float sq[K_SZ];
    if (tid < K_SZ) sq[tid] = query[b * K_SZ + tid];
    __syncthreads();
    if (tid < H1) {
        float acc = b1[tid];
#pragma unroll 8
        for (int i = 0; i < K_SZ; ++i)
            acc += sq[i] * (W1[i * H1 + tid] + W1[(128 + i) * H1 + tid]);
        qW[b * H1 + tid] = acc;
    }
}

// ---------------- pack weights:
// W1kG/W1pG (f32, frag order, 10 frags): f = ht*2+ks; k = ks*32+(l>>4)*8+j; h = ht*16+(l&15)
//   W1kG = W1b - W1c (k coefficient), W1pG = W1d (q*k coefficient)
// Bp2 (fp16 frag image, 9 frags): f2 = ht2*3+ks2 (zero-padded K 80->96, N 40->48)
__global__ __launch_bounds__(256) void prep_bp(const float* __restrict__ W1,
                                               const float* __restrict__ W2,
                                               float* __restrict__ W1kG,
                                               float* __restrict__ W1pG,
                                               _Float16* __restrict__ Bp2) {
    int idx = blockIdx.x * 256 + threadIdx.x;
    if (idx < W1ELT) {
        int j = idx & 7, lane = (idx >> 3) & 63, f = idx >> 9;
        int ks = f & 1, ht = f >> 1;
        int k = ks * 32 + (lane >> 4) * 8 + j;
        int h = ht * 16 + (lane & 15);
        W1kG[idx] = W1[(64 + k) * H1 + h] - W1[(128 + k) * H1 + h];
        W1pG[idx] = W1[(192 + k) * H1 + h];
    } else {
        int idx2 = idx - W1ELT;
        if (idx2 < W2HALVES) {
            int j = idx2 & 7, lane = (idx2 >> 3) & 63, f2 = idx2 >> 9;
            int ks2 = f2 % 3, ht2 = f2 / 3;
            int k2 = ks2 * 32 + (lane >> 4) * 8 + j;
            int m = ht2 * 16 + (lane & 15);
            float w = (k2 < H1 && m < H2) ? W2[k2 * H2 + m] : 0.0f;
            Bp2[idx2] = (_Float16)w;
        }
    }
}

// ---------------- fully fused: per-block W_eff = W1k + q.*W1p (fp32 combine ->
// fp16, in LDS), W2 frags DMA->LDS. Layer-1 K=64 (10 MFMA/tile), layer-2 9.
// 4-slot {4,3,3,3}, masked softmax + value-weighted sum.
__global__ __launch_bounds__(256, 4) void fused_kernel(
    const float* __restrict__ query, const float* __restrict__ key,
    const float* __restrict__ value, const int* __restrict__ mask,
    const float* __restrict__ W1kG, const float* __restrict__ W1pG,
    const _Float16* __restrict__ Bp2G,
    const float* __restrict__ a1, const float* __restrict__ b2,
    const float* __restrict__ a2, const float* __restrict__ Wo,
    const float* __restrict__ bo, const float* __restrict__ qW,
    float* __restrict__ out) {
    __shared__ _Float16 wlds[WLDS_HALVES];   // [0,5120): W_eff  [5120,9728): W2
    __shared__ float sq[K_SZ];
    __shared__ float sqW[H1];
    __shared__ float sa1[H1];
    __shared__ float sb2[48], sa2[48], sWo[48];
    __shared__ float sprob[256];
    __shared__ float sred[8];
    __shared__ float spart[4 * K_SZ];

    const int tid = threadIdx.x;
    const int wv = tid >> 6;
    const int l = tid & 63;
    const int l15 = l & 15;
    const int lg = l >> 4;
    const int b = blockIdx.x;
    const int p0 = b * N_SZ;
    const int NT = (wv == 0) ? 4 : 3;
    const int tb = (wv == 0) ? 0 : 1 + wv * 3;

    // ---- W2 frag DMA -> wlds[5120..]: 576 16B chunks, linear dest
    {
#pragma unroll
        for (int i = 0; i < 2; ++i) {
            int cb = i * 256 + wv * 64;
            gload16(&Bp2G[(size_t)(cb + l) * 8], (char*)&wlds[W1ELT] + (size_t)cb * 16);
        }
        if (wv == 0) {
            int cb = 512;
            gload16(&Bp2G[(size_t)(cb + l) * 8], (char*)&wlds[W1ELT] + (size_t)cb * 16);
        }
    }

    // ---- stage params
    if (tid < K_SZ) sq[tid] = query[b * K_SZ + tid];
    if (tid < H1) { sqW[tid] = qW[b * H1 + tid]; sa1[tid] = a1[tid]; }
    if (tid >= 128 && tid < 176) {
        int i = tid - 128;
        sb2[i] = (i < H2) ? b2[i] : 0.0f;
        sa2[i] = (i < H2) ? a2[i] : 0.0f;
        sWo[i] = (i < H2) ? Wo[i] : 0.0f;
    }
    float bov = bo[0];
    __syncthreads();   // sq visible; W2 DMA drained

    // ---- W_eff = W1k + q[k]*W1p (f32 combine, one fp16 round), 20 elts/thread
#pragma unroll
    for (int r = 0; r < 20; ++r) {
        int idx = r * 256 + tid;            // 0..5119
        int j = idx & 7, lane = (idx >> 3) & 63, f = idx >> 9;
        int k = (f & 1) * 32 + ((lane >> 4) * 8) + j;
        float w = W1kG[idx] + sq[k] * W1pG[idx];
        wlds[idx] = (_Float16)w;
    }
    __syncthreads();

    const int wofs = l * 8;   // lane offset within a frag (halves), linear

    // ---- layer 1: D1[f][n] = sum_k W_eff[k][f] * K[k][n]   (K = 64)
    f32x4 D1[4][5];
#pragma unroll
    for (int i = 0; i < 4; ++i)
#pragma unroll
        for (int ht = 0; ht < 5; ++ht) D1[i][ht] = (f32x4){0.f, 0.f, 0.f, 0.f};

    f16x8 Bk[4][2];
#pragma unroll
    for (int i = 0; i < 4; ++i) {
        if (i < NT) {
            int nloc = (tb + i) * 16 + l15;
            int pg = p0 + nloc;
            int pgc = (pg < B_SZ * N_SZ) ? pg : (B_SZ * N_SZ - 1);
#pragma unroll
            for (int ksp = 0; ksp < 2; ++ksp) {
                const float* kp = &key[(size_t)pgc * K_SZ + ksp * 32 + lg * 8];
                float4 k0 = *reinterpret_cast<const float4*>(kp);
                float4 k1 = *reinterpret_cast<const float4*>(kp + 4);
                f16x8 bk;
                bk[0] = (_Float16)k0.x; bk[1] = (_Float16)k0.y; bk[2] = (_Float16)k0.z; bk[3] = (_Float16)k0.w;
                bk[4] = (_Float16)k1.x; bk[5] = (_Float16)k1.y; bk[6] = (_Float16)k1.z; bk[7] = (_Float16)k1.w;
                Bk[i][ksp] = bk;
            }
        }
    }
#pragma unroll
    for (int ht = 0; ht < 5; ++ht) {
#pragma unroll
        for (int ks = 0; ks < 2; ++ks) {
            f16x8 wh = *reinterpret_cast<const f16x8*>(&wlds[(ht * 2 + ks) * 512 + wofs]);
#pragma unroll
            for (int i = 0; i < 4; ++i) {
                if (i < NT) {
                    D1[i][ht] = __builtin_amdgcn_mfma_f32_16x16x32_f16(wh, Bk[i][ks], D1[i][ht], 0, 0, 0);
                }
            }
        }
    }

    // ---- epilogue 1 (in-register): h1 = prelu(D1 + qW), pack to fp16 pairs
    u32 pk[4][6][2];
#pragma unroll
    for (int i = 0; i < 4; ++i) {
        if (i < NT) {
#pragma unroll
            for (int ht = 0; ht < 5; ++ht) {
                float4 qw4 = *reinterpret_cast<const float4*>(&sqW[ht * 16 + lg * 4]);
                float4 aa4 = *reinterpret_cast<const float4*>(&sa1[ht * 16 + lg * 4]);
                float h0 = D1[i][ht][0] + qw4.x;
                float h1v = D1[i][ht][1] + qw4.y;
                float h2 = D1[i][ht][2] + qw4.z;
                float h3 = D1[i][ht][3] + qw4.w;
                h0 = (h0 > 0.f) ? h0 : h0 * aa4.x;
                h1v = (h1v > 0.f) ? h1v : h1v * aa4.y;
                h2 = (h2 > 0.f) ? h2 : h2 * aa4.z;
                h3 = (h3 > 0.f) ? h3 : h3 * aa4.w;
                H2U u0, u1;
                u0.h[0] = (_Float16)h0; u0.h[1] = (_Float16)h1v;
                u1.h[0] = (_Float16)h2; u1.h[1] = (_Float16)h3;
                pk[i][ht][0] = u0.u;
                pk[i][ht][1] = u1.u;
            }
            pk[i][5][0] = 0u; pk[i][5][1] = 0u;   // zero-pad feats 80..95
        }
    }

    // ---- layer 2: D2[m][n] = sum_k2 W2[k2][m] * h1[k2][n]
    f32x4 D2[4][3];
#pragma unroll
    for (int i = 0; i < 4; ++i)
#pragma unroll
        for (int ht = 0; ht < 3; ++ht) D2[i][ht] = (f32x4){0.f, 0.f, 0.f, 0.f};

#pragma unroll
    for (int ks2 = 0; ks2 < 3; ++ks2) {
        f16x8 B2f[4];
#pragma unroll
        for (int i = 0; i < 4; ++i) {
            if (i < NT) {
                U4F bu;
#pragma unroll
                for (int q = 0; q < 4; ++q) {
                    int src = ((lg * 2 + (q >> 1)) & 3) * 16 + l15;
                    u32 va = (u32)__shfl((int)pk[i][ks2 * 2][q & 1], src, 64);
                    u32 vb = (u32)__shfl((int)pk[i][ks2 * 2 + 1][q & 1], src, 64);
                    bu.u[q] = (lg < 2) ? va : vb;
                }
                B2f[i] = bu.v;
            }
        }
#pragma unroll
        for (int ht2 = 0; ht2 < 3; ++ht2) {
            f16x8 wh = *reinterpret_cast<const f16x8*>(&wlds[W1ELT + (ht2 * 3 + ks2) * 512 + wofs]);
#pragma unroll
            for (int i = 0; i < 4; ++i) {
                if (i < NT) {
                    D2[i][ht2] = __builtin_amdgcn_mfma_f32_16x16x32_f16(wh, B2f[i], D2[i][ht2], 0, 0, 0);
                }
            }
        }
    }

    // ---- epilogue 2 + layer 3: score(n) = bo + sum_m Wo[m]*prelu(D2[m][n]+b2[m])
#pragma unroll
    for (int i = 0; i < 4; ++i) {
        if (i < NT) {
            float psum = 0.f;
#pragma unroll
            for (int ht2 = 0; ht2 < 3; ++ht2) {
                float4 b4 = *reinterpret_cast<const float4*>(&sb2[ht2 * 16 + lg * 4]);
                float4 a4 = *reinterpret_cast<const float4*>(&sa2[ht2 * 16 + lg * 4]);
                float4 w4 = *reinterpret_cast<const float4*>(&sWo[ht2 * 16 + lg * 4]);
                float v0 = D2[i][ht2][0] + b4.x;
                float v1 = D2[i][ht2][1] + b4.y;
                float v2 = D2[i][ht2][2] + b4.z;
                float v3 = D2[i][ht2][3] + b4.w;
                v0 = (v0 > 0.f) ? v0 : v0 * a4.x;
                v1 = (v1 > 0.f) ? v1 : v1 * a4.y;
                v2 = (v2 > 0.f) ? v2 : v2 * a4.z;
                v3 = (v3 > 0.f) ? v3 : v3 * a4.w;
                psum += v0 * w4.x + v1 * w4.y + v2 * w4.z + v3 * w4.w;
            }
            psum += __shfl_xor(psum, 16);
            psum += __shfl_xor(psum, 32);
            if (lg == 0) {
                int nloc = (tb + i) * 16 + l15;
                float sv;
                if (nloc < N_SZ) sv = (mask[p0 + nloc] == 0) ? NEG_V : (psum + bov);
                else sv = -INFINITY;
                sprob[nloc] = sv;
            }
        }
    }
    __syncthreads();

    // ---- softmax over the 208 staged scores (pads are -inf)
    float s = (tid < 208) ? sprob[tid] : -INFINITY;
    float m = s;
#pragma unroll
    for (int off = 32; off >= 1; off >>= 1) m = fmaxf(m, __shfl_xor(m, off));
    if ((tid & 63) == 0) sred[tid >> 6] = m;
    __syncthreads();
    m = fmaxf(fmaxf(sred[0], sred[1]), fmaxf(sred[2], sred[3]));

    float e = (tid < 208) ? expf(s - m) : 0.0f;
    sprob[tid] = e;
    float t = e;
#pragma unroll
    for (int off = 32; off >= 1; off >>= 1) t += __shfl_xor(t, off);
    if ((tid & 63) == 0) sred[4 + (tid >> 6)] = t;
    __syncthreads();
    float inv = 1.0f / (sred[4] + sred[5] + sred[6] + sred[7]);

    // ---- weighted value sum: wave wv covers n = [50wv, 50wv+50), lane = k index
    float acc0 = 0.0f, acc1v = 0.0f;
#pragma unroll 5
    for (int jj = 0; jj < 50; jj += 2) {
        int n = wv * 50 + jj;
        acc0  += sprob[n]     * value[((size_t)p0 + n)     * K_SZ + l];
        acc1v += sprob[n + 1] * value[((size_t)p0 + n + 1) * K_SZ + l];
    }
    spart[wv * K_SZ + l] = acc0 + acc1v;
    __syncthreads();
    if (tid < K_SZ) {
        out[b * K_SZ + tid] =
            (spart[tid] + spart[64 + tid] + spart[128 + tid] + spart[192 + tid]) * inv;
    }
}

extern "C" void kernel_launch(void* const* d_in, const int* in_sizes, int n_in,
                              void* d_out, int out_size, void* d_ws, size_t ws_size,
                              hipStream_t stream) {
    const float* query = (const float*)d_in[0];
    const float* key   = (const float*)d_in[1];
    const float* value = (const float*)d_in[2];
    const int*   mask  = (const int*)d_in[3];
    const float* W1    = (const float*)d_in[4];
    const float* b1    = (const float*)d_in[5];
    const float* a1    = (const float*)d_in[6];
    const float* W2    = (const float*)d_in[7];
    const float* b2    = (const float*)d_in[8];
    const float* a2    = (const float*)d_in[9];
    const float* Wo    = (const float*)d_in[10];
    const float* bo    = (const float*)d_in[11];
    float* out = (float*)d_out;

    float* qW      = (float*)d_ws;                       // B*H1 f32
    float* W1kG    = qW + (size_t)B_SZ * H1;             // 5120 f32
    float* W1pG    = W1kG + W1ELT;                       // 5120 f32
    _Float16* Bp2  = (_Float16*)(W1pG + W1ELT);          // 4608 halves

    qw_kernel<<<B_SZ, 128, 0, stream>>>(query, W1, b1, qW);
    prep_bp<<<(W1ELT + W2HALVES + 255) / 256, 256, 0, stream>>>(W1, W2, W1kG, W1pG, Bp2);
    fused_kernel<<<B_SZ, 256, 0, stream>>>(
        query, key, value, mask, W1kG, W1pG, Bp2, a1, b2, a2, Wo, bo, qW, out);
}

// Round 19
// 132.101 us; speedup vs baseline: 7.1331x; 1.0136x over previous
//
#include <hip/hip_runtime.h>
#include <math.h>

#define B_SZ 4096
#define N_SZ 200
#define K_SZ 64
#define H1 80
#define H2 40
#define NEG_V (-4294967295.0f)

#define NW1FRAG 10               // layer-1 W_eff frags (K=64: 2 ks x 5 ht)
#define NW2FRAG 9                // layer-2 frags (3 ks2 x 3 ht2)
#define W1ELT (NW1FRAG * 512)    // 5120 elements
#define W2HALVES (NW2FRAG * 512) // 4608 fp16 halves
#define WLDS_HALVES (W1ELT + W2HALVES)  // 9728 halves = 19,456 B

typedef _Float16 f16x8 __attribute__((ext_vector_type(8)));
typedef float f32x4 __attribute__((ext_vector_type(4)));
typedef unsigned int u32;

union H2U { _Float16 h[2]; u32 u; };
union U4F { u32 u[4]; f16x8 v; };

typedef __attribute__((address_space(3))) u32 lds_u32;
typedef const __attribute__((address_space(1))) u32 glb_u32;

__device__ __forceinline__ void gload16(const void* gp, void* lp) {
    __builtin_amdgcn_global_load_lds((glb_u32*)gp, (lds_u32*)lp, 16, 0, 0);
}

// ---------------- qW[b][h] = b1[h] + sum_i q[b][i]*(W1[i][h]+W1[128+i][h])  (exact fp32)
__global__ __launch_bounds__(128) void qw_kernel(const float* __restrict__ query,
                                                 const float* __restrict__ W1,
                                                 const float* __restrict__ b1,
                                                 float* __restrict__ qW) {
    int b = blockIdx.x;
    int tid = threadIdx.x;
    __shared__ float sq[K_SZ];
    if (tid < K_SZ) sq[tid] = query[b * K_SZ + tid];
    __syncthreads();
    if (tid < H1) {
        float acc = b1[tid];
#pragma unroll 8
        for (int i = 0; i < K_SZ; ++i)
            acc += sq[i] * (W1[i * H1 + tid] + W1[(128 + i) * H1 + tid]);
        qW[b * H1 + tid] = acc;
    }
}

// ---------------- pack weights (same layouts as R18)
__global__ __launch_bounds__(256) void prep_bp(const float* __restrict__ W1,
                                               const float* __restrict__ W2,
                                               float* __restrict__ W1kG,
                                               float* __restrict__ W1pG,
                                               _Float16* __restrict__ Bp2) {
    int idx = blockIdx.x * 256 + threadIdx.x;
    if (idx < W1ELT) {
        int j = idx & 7, lane = (idx >> 3) & 63, f = idx >> 9;
        int ks = f & 1, ht = f >> 1;
        int k = ks * 32 + (lane >> 4) * 8 + j;
        int h = ht * 16 + (lane & 15);
        W1kG[idx] = W1[(64 + k) * H1 + h] - W1[(128 + k) * H1 + h];
        W1pG[idx] = W1[(192 + k) * H1 + h];
    } else {
        int idx2 = idx - W1ELT;
        if (idx2 < W2HALVES) {
            int j = idx2 & 7, lane = (idx2 >> 3) & 63, f2 = idx2 >> 9;
            int ks2 = f2 % 3, ht2 = f2 / 3;
            int k2 = ks2 * 32 + (lane >> 4) * 8 + j;
            int m = ht2 * 16 + (lane & 15);
            float w = (k2 < H1 && m < H2) ? W2[k2 * H2 + m] : 0.0f;
            Bp2[idx2] = (_Float16)w;
        }
    }
}

// ---------------- fully fused: W_eff fold + MFMA scores + softmax + value sum,
// with value prefetched to LDS via linear DMA issued under the MFMA phase.
__global__ __launch_bounds__(256, 2) void fused_kernel(
    const float* __restrict__ query, const float* __restrict__ key,
    const float* __restrict__ value, const int* __restrict__ mask,
    const float* __restrict__ W1kG, const float* __restrict__ W1pG,
    const _Float16* __restrict__ Bp2G,
    const float* __restrict__ a1, const float* __restrict__ b2,
    const float* __restrict__ a2, const float* __restrict__ Wo,
    const float* __restrict__ bo, const float* __restrict__ qW,
    float* __restrict__ out) {
    __shared__ _Float16 wlds[WLDS_HALVES];   // [0,5120): W_eff  [5120,9728): W2
    __shared__ float vbuf[N_SZ * K_SZ];      // 51,200 B value tile [200][64]
    __shared__ float sq[K_SZ];
    __shared__ float sqW[H1];
    __shared__ float sa1[H1];
    __shared__ float sb2[48], sa2[48], sWo[48];
    __shared__ float sprob[256];
    __shared__ float sred[8];
    __shared__ float spart[4 * K_SZ];

    const int tid = threadIdx.x;
    const int wv = tid >> 6;
    const int l = tid & 63;
    const int l15 = l & 15;
    const int lg = l >> 4;
    const int b = blockIdx.x;
    const int p0 = b * N_SZ;
    const int NT = (wv == 0) ? 4 : 3;
    const int tb = (wv == 0) ? 0 : 1 + wv * 3;

    // ---- W2 frag DMA -> wlds[5120..]: 576 16B chunks, linear dest
    {
#pragma unroll
        for (int i = 0; i < 2; ++i) {
            int cb = i * 256 + wv * 64;
            gload16(&Bp2G[(size_t)(cb + l) * 8], (char*)&wlds[W1ELT] + (size_t)cb * 16);
        }
        if (wv == 0) {
            int cb = 512;
            gload16(&Bp2G[(size_t)(cb + l) * 8], (char*)&wlds[W1ELT] + (size_t)cb * 16);
        }
    }

    // ---- stage params
    if (tid < K_SZ) sq[tid] = query[b * K_SZ + tid];
    if (tid < H1) { sqW[tid] = qW[b * H1 + tid]; sa1[tid] = a1[tid]; }
    if (tid >= 128 && tid < 176) {
        int i = tid - 128;
        sb2[i] = (i < H2) ? b2[i] : 0.0f;
        sa2[i] = (i < H2) ? a2[i] : 0.0f;
        sWo[i] = (i < H2) ? Wo[i] : 0.0f;
    }
    float bov = bo[0];
    __syncthreads();   // A: sq visible; W2 DMA drained

    // ---- W_eff = W1k + q[k]*W1p (f32 combine, one fp16 round), 20 elts/thread
#pragma unroll
    for (int r = 0; r < 20; ++r) {
        int idx = r * 256 + tid;            // 0..5119
        int j = idx & 7, lane = (idx >> 3) & 63, f = idx >> 9;
        int k = (f & 1) * 32 + ((lane >> 4) * 8) + j;
        float w = W1kG[idx] + sq[k] * W1pG[idx];
        wlds[idx] = (_Float16)w;
    }
    __syncthreads();   // B: W_eff visible (drains only W1k/W1p reads, already used)

    const int wofs = l * 8;   // lane offset within a frag (halves), linear

    // ---- issue key loads FIRST (results needed soon; complete before DMA in order)
    f16x8 Bk[4][2];
#pragma unroll
    for (int i = 0; i < 4; ++i) {
        if (i < NT) {
            int nloc = (tb + i) * 16 + l15;
            int pg = p0 + nloc;
            int pgc = (pg < B_SZ * N_SZ) ? pg : (B_SZ * N_SZ - 1);
#pragma unroll
            for (int ksp = 0; ksp < 2; ++ksp) {
                const float* kp = &key[(size_t)pgc * K_SZ + ksp * 32 + lg * 8];
                float4 k0 = *reinterpret_cast<const float4*>(kp);
                float4 k1 = *reinterpret_cast<const float4*>(kp + 4);
                f16x8 bk;
                bk[0] = (_Float16)k0.x; bk[1] = (_Float16)k0.y; bk[2] = (_Float16)k0.z; bk[3] = (_Float16)k0.w;
                bk[4] = (_Float16)k1.x; bk[5] = (_Float16)k1.y; bk[6] = (_Float16)k1.z; bk[7] = (_Float16)k1.w;
                Bk[i][ksp] = bk;
            }
        }
    }

    // ---- issue value DMA -> vbuf (3200 16B chunks, linear source AND dest);
    // drains at barrier C, hidden under the MFMA/epilogue phase.
    {
        const float* vsrc = &value[(size_t)p0 * K_SZ];
        int g0 = wv * 800;
#pragma unroll
        for (int i = 0; i < 13; ++i) {
            if (i * 64 + l < 800) {
                int cb = g0 + i * 64;
                gload16(&vsrc[(size_t)(cb + l) * 4], (char*)vbuf + (size_t)cb * 16);
            }
        }
    }

    // ---- layer 1: D1[f][n] = sum_k W_eff[k][f] * K[k][n]   (K = 64)
    f32x4 D1[4][5];
#pragma unroll
    for (int i = 0; i < 4; ++i)
#pragma unroll
        for (int ht = 0; ht < 5; ++ht) D1[i][ht] = (f32x4){0.f, 0.f, 0.f, 0.f};
#pragma unroll
    for (int ht = 0; ht < 5; ++ht) {
#pragma unroll
        for (int ks = 0; ks < 2; ++ks) {
            f16x8 wh = *reinterpret_cast<const f16x8*>(&wlds[(ht * 2 + ks) * 512 + wofs]);
#pragma unroll
            for (int i = 0; i < 4; ++i) {
                if (i < NT) {
                    D1[i][ht] = __builtin_amdgcn_mfma_f32_16x16x32_f16(wh, Bk[i][ks], D1[i][ht], 0, 0, 0);
                }
            }
        }
    }

    // ---- epilogue 1 (in-register): h1 = prelu(D1 + qW), pack to fp16 pairs
    u32 pk[4][6][2];
#pragma unroll
    for (int i = 0; i < 4; ++i) {
        if (i < NT) {
#pragma unroll
            for (int ht = 0; ht < 5; ++ht) {
                float4 qw4 = *reinterpret_cast<const float4*>(&sqW[ht * 16 + lg * 4]);
                float4 aa4 = *reinterpret_cast<const float4*>(&sa1[ht * 16 + lg * 4]);
                float h0 = D1[i][ht][0] + qw4.x;
                float h1v = D1[i][ht][1] + qw4.y;
                float h2 = D1[i][ht][2] + qw4.z;
                float h3 = D1[i][ht][3] + qw4.w;
                h0 = (h0 > 0.f) ? h0 : h0 * aa4.x;
                h1v = (h1v > 0.f) ? h1v : h1v * aa4.y;
                h2 = (h2 > 0.f) ? h2 : h2 * aa4.z;
                h3 = (h3 > 0.f) ? h3 : h3 * aa4.w;
                H2U u0, u1;
                u0.h[0] = (_Float16)h0; u0.h[1] = (_Float16)h1v;
                u1.h[0] = (_Float16)h2; u1.h[1] = (_Float16)h3;
                pk[i][ht][0] = u0.u;
                pk[i][ht][1] = u1.u;
            }
            pk[i][5][0] = 0u; pk[i][5][1] = 0u;   // zero-pad feats 80..95
        }
    }

    // ---- layer 2: D2[m][n] = sum_k2 W2[k2][m] * h1[k2][n]
    f32x4 D2[4][3];
#pragma unroll
    for (int i = 0; i < 4; ++i)
#pragma unroll
        for (int ht = 0; ht < 3; ++ht) D2[i][ht] = (f32x4){0.f, 0.f, 0.f, 0.f};
#pragma unroll
    for (int ks2 = 0; ks2 < 3; ++ks2) {
        f16x8 B2f[4];
#pragma unroll
        for (int i = 0; i < 4; ++i) {
            if (i < NT) {
                U4F bu;
#pragma unroll
                for (int q = 0; q < 4; ++q) {
                    int src = ((lg * 2 + (q >> 1)) & 3) * 16 + l15;
                    u32 va = (u32)__shfl((int)pk[i][ks2 * 2][q & 1], src, 64);
                    u32 vb = (u32)__shfl((int)pk[i][ks2 * 2 + 1][q & 1], src, 64);
                    bu.u[q] = (lg < 2) ? va : vb;
                }
                B2f[i] = bu.v;
            }
        }
#pragma unroll
        for (int ht2 = 0; ht2 < 3; ++ht2) {
            f16x8 wh = *reinterpret_cast<const f16x8*>(&wlds[W1ELT + (ht2 * 3 + ks2) * 512 + wofs]);
#pragma unroll
            for (int i = 0; i < 4; ++i) {
                if (i < NT) {
                    D2[i][ht2] = __builtin_amdgcn_mfma_f32_16x16x32_f16(wh, B2f[i], D2[i][ht2], 0, 0, 0);
                }
            }
        }
    }

    // ---- epilogue 2 + layer 3: score(n) = bo + sum_m Wo[m]*prelu(D2[m][n]+b2[m])
#pragma unroll
    for (int i = 0; i < 4; ++i) {
        if (i < NT) {
            float psum = 0.f;
#pragma unroll
            for (int ht2 = 0; ht2 < 3; ++ht2) {
                float4 b4 = *reinterpret_cast<const float4*>(&sb2[ht2 * 16 + lg * 4]);
                float4 a4 = *reinterpret_cast<const float4*>(&sa2[ht2 * 16 + lg * 4]);
                float4 w4 = *reinterpret_cast<const float4*>(&sWo[ht2 * 16 + lg * 4]);
                float v0 = D2[i][ht2][0] + b4.x;
                float v1 = D2[i][ht2][1] + b4.y;
                float v2 = D2[i][ht2][2] + b4.z;
                float v3 = D2[i][ht2][3] + b4.w;
                v0 = (v0 > 0.f) ? v0 : v0 * a4.x;
                v1 = (v1 > 0.f) ? v1 : v1 * a4.y;
                v2 = (v2 > 0.f) ? v2 : v2 * a4.z;
                v3 = (v3 > 0.f) ? v3 : v3 * a4.w;
                psum += v0 * w4.x + v1 * w4.y + v2 * w4.z + v3 * w4.w;
            }
            psum += __shfl_xor(psum, 16);
            psum += __shfl_xor(psum, 32);
            if (lg == 0) {
                int nloc = (tb + i) * 16 + l15;
                float sv;
                if (nloc < N_SZ) sv = (mask[p0 + nloc] == 0) ? NEG_V : (psum + bov);
                else sv = -INFINITY;
                sprob[nloc] = sv;
            }
        }
    }
    __syncthreads();   // C: scores staged; value DMA drained (hidden under MFMA)

    // ---- softmax over the 208 staged scores (pads are -inf)
    float s = (tid < 208) ? sprob[tid] : -INFINITY;
    float m = s;
#pragma unroll
    for (int off = 32; off >= 1; off >>= 1) m = fmaxf(m, __shfl_xor(m, off));
    if ((tid & 63) == 0) sred[tid >> 6] = m;
    __syncthreads();
    m = fmaxf(fmaxf(sred[0], sred[1]), fmaxf(sred[2], sred[3]));

    float e = (tid < 208) ? expf(s - m) : 0.0f;
    sprob[tid] = e;
    float t = e;
#pragma unroll
    for (int off = 32; off >= 1; off >>= 1) t += __shfl_xor(t, off);
    if ((tid & 63) == 0) sred[4 + (tid >> 6)] = t;
    __syncthreads();
    float inv = 1.0f / (sred[4] + sred[5] + sred[6] + sred[7]);

    // ---- weighted value sum FROM LDS: wave wv covers n = [50wv, 50wv+50)
    float acc0 = 0.0f, acc1v = 0.0f;
#pragma unroll 5
    for (int jj = 0; jj < 50; jj += 2) {
        int n = wv * 50 + jj;
        acc0  += sprob[n]     * vbuf[n * K_SZ + l];
        acc1v += sprob[n + 1] * vbuf[(n + 1) * K_SZ + l];
    }
    spart[wv * K_SZ + l] = acc0 + acc1v;
    __syncthreads();
    if (tid < K_SZ) {
        out[b * K_SZ + tid] =
            (spart[tid] + spart[64 + tid] + spart[128 + tid] + spart[192 + tid]) * inv;
    }
}

extern "C" void kernel_launch(void* const* d_in, const int* in_sizes, int n_in,
                              void* d_out, int out_size, void* d_ws, size_t ws_size,
                              hipStream_t stream) {
    const float* query = (const float*)d_in[0];
    const float* key   = (const float*)d_in[1];
    const float* value = (const float*)d_in[2];
    const int*   mask  = (const int*)d_in[3];
    const float* W1    = (const float*)d_in[4];
    const float* b1    = (const float*)d_in[5];
    const float* a1    = (const float*)d_in[6];
    const float* W2    = (const float*)d_in[7];
    const float* b2    = (const float*)d_in[8];
    const float* a2    = (const float*)d_in[9];
    const float* Wo    = (const float*)d_in[10];
    const float* bo    = (const float*)d_in[11];
    float* out = (float*)d_out;

    float* qW      = (float*)d_ws;                       // B*H1 f32
    float* W1kG    = qW + (size_t)B_SZ * H1;             // 5120 f32
    float* W1pG    = W1kG + W1ELT;                       // 5120 f32
    _Float16* Bp2  = (_Float16*)(W1pG + W1ELT);          // 4608 halves

    qw_kernel<<<B_SZ, 128, 0, stream>>>(query, W1, b1, qW);
    prep_bp<<<(W1ELT + W2HALVES + 255) / 256, 256, 0, stream>>>(W1, W2, W1kG, W1pG, Bp2);
    fused_kernel<<<B_SZ, 256, 0, stream>>>(
        query, key, value, mask, W1kG, W1pG, Bp2, a1, b2, a2, Wo, bo, qW, out);
}